// Round 1
// baseline (3385.207 us; speedup 1.0000x reference)
//
#include <hip/hip_runtime.h>
#include <math.h>

#define N_NODES 100000
#define N_EDGES 1600000
#define F_IN 128
#define H_DIM 128
#define C_OUT 40
#define BN_EPS 1e-5f

// ---------------- degree / norm ----------------
__global__ __launch_bounds__(256) void deg_init(float* deg) {
    int i = blockIdx.x * 256 + threadIdx.x;
    if (i < N_NODES) deg[i] = 1.0f;   // self-loop
}

__global__ __launch_bounds__(256) void deg_count(const int* __restrict__ dst,
                                                 float* __restrict__ deg) {
    int e = blockIdx.x * 256 + threadIdx.x;
    if (e < N_EDGES) atomicAdd(&deg[dst[e]], 1.0f);
}

__global__ __launch_bounds__(256) void deg_rsqrt(float* deg) {
    int i = blockIdx.x * 256 + threadIdx.x;
    if (i < N_NODES) deg[i] = rsqrtf(deg[i]);   // deg >= 1 always
}

// ---------------- GEMM1: h1 = x @ W1  (f32, W1 in LDS) ----------------
// block: 256 threads -> 64 rows x 128 cols; thread: 4 rows x 8 cols
__global__ __launch_bounds__(256) void gemm1(const float* __restrict__ x,
                                             const float* __restrict__ W,
                                             float* __restrict__ h) {
    __shared__ float Ws[F_IN * H_DIM];   // [k][j], 64 KB
    for (int i = threadIdx.x; i < F_IN * H_DIM / 4; i += 256)
        ((float4*)Ws)[i] = ((const float4*)W)[i];
    __syncthreads();

    int ty = threadIdx.x >> 4;    // 0..15 (row group of 4)
    int tx = threadIdx.x & 15;    // 0..15 (col group: tx*4 and 64+tx*4)
    int row0 = blockIdx.x * 64 + ty * 4;

    int r[4];
    #pragma unroll
    for (int i = 0; i < 4; ++i) {
        int rr = row0 + i;
        r[i] = rr < N_NODES ? rr : N_NODES - 1;
    }

    float acc[4][8] = {};
    for (int k = 0; k < F_IN; k += 4) {
        float4 xv[4];
        #pragma unroll
        for (int i = 0; i < 4; ++i)
            xv[i] = *(const float4*)(x + (size_t)r[i] * F_IN + k);
        #pragma unroll
        for (int kk = 0; kk < 4; ++kk) {
            float4 w0 = *(const float4*)&Ws[(k + kk) * H_DIM + tx * 4];
            float4 w1 = *(const float4*)&Ws[(k + kk) * H_DIM + 64 + tx * 4];
            #pragma unroll
            for (int i = 0; i < 4; ++i) {
                float xs = (&xv[i].x)[kk];
                acc[i][0] = fmaf(xs, w0.x, acc[i][0]);
                acc[i][1] = fmaf(xs, w0.y, acc[i][1]);
                acc[i][2] = fmaf(xs, w0.z, acc[i][2]);
                acc[i][3] = fmaf(xs, w0.w, acc[i][3]);
                acc[i][4] = fmaf(xs, w1.x, acc[i][4]);
                acc[i][5] = fmaf(xs, w1.y, acc[i][5]);
                acc[i][6] = fmaf(xs, w1.z, acc[i][6]);
                acc[i][7] = fmaf(xs, w1.w, acc[i][7]);
            }
        }
    }
    #pragma unroll
    for (int i = 0; i < 4; ++i) {
        int rr = row0 + i;
        if (rr < N_NODES) {
            float4 o0 = {acc[i][0], acc[i][1], acc[i][2], acc[i][3]};
            float4 o1 = {acc[i][4], acc[i][5], acc[i][6], acc[i][7]};
            *(float4*)(h + (size_t)rr * H_DIM + tx * 4) = o0;
            *(float4*)(h + (size_t)rr * H_DIM + 64 + tx * 4) = o1;
        }
    }
}

// ---------------- scatter layer 1: agg[dst] += h[src]*norm (128 ch) -------
// 32 threads per edge, 4 channels each. Edges [E, E+N) are self-loops.
__global__ __launch_bounds__(256) void scatter1(const int* __restrict__ src,
                                                const int* __restrict__ dst,
                                                const float* __restrict__ dinv,
                                                const float* __restrict__ h,
                                                float* __restrict__ agg) {
    int gid = blockIdx.x * 256 + threadIdx.x;   // < 54.4M
    int e = gid >> 5;
    if (e >= N_EDGES + N_NODES) return;
    int c4 = (gid & 31) * 4;
    int s, d; float w;
    if (e < N_EDGES) {
        s = src[e]; d = dst[e];
        w = dinv[s] * dinv[d];
    } else {
        s = d = e - N_EDGES;
        float dv = dinv[s];
        w = dv * dv;
    }
    float4 v = *(const float4*)(h + (size_t)s * H_DIM + c4);
    float* o = agg + (size_t)d * H_DIM + c4;
    atomicAdd(o + 0, v.x * w);
    atomicAdd(o + 1, v.y * w);
    atomicAdd(o + 2, v.z * w);
    atomicAdd(o + 3, v.w * w);
}

// ---------------- bias + relu (in place) + BN batch stats ----------------
__global__ __launch_bounds__(256) void relu_stats(float* __restrict__ agg,
                                                  const float* __restrict__ b1,
                                                  float* __restrict__ sums,
                                                  float* __restrict__ sumsq) {
    int tid = blockIdx.x * 256 + threadIdx.x;
    int stride = gridDim.x * 256;               // multiple of 128
    int c = tid & (H_DIM - 1);                  // channel constant per thread
    float b = b1[c];
    float s = 0.f, sq = 0.f;
    for (long long i = tid; i < (long long)N_NODES * H_DIM; i += stride) {
        float v = agg[i] + b;
        v = fmaxf(v, 0.f);
        agg[i] = v;
        s += v;
        sq += v * v;
    }
    atomicAdd(&sums[c], s);
    atomicAdd(&sumsq[c], sq);
}

__global__ void bn_final(const float* __restrict__ sums,
                         const float* __restrict__ sumsq,
                         const float* __restrict__ gamma,
                         const float* __restrict__ beta,
                         float* __restrict__ scale,
                         float* __restrict__ shift) {
    int c = threadIdx.x;
    if (c < H_DIM) {
        const float invn = 1.0f / (float)N_NODES;
        float mean = sums[c] * invn;
        float var = sumsq[c] * invn - mean * mean;
        float sc = gamma[c] * rsqrtf(var + BN_EPS);
        scale[c] = sc;
        shift[c] = beta[c] - mean * sc;
    }
}

// ---------------- GEMM2: h2 = (relu*scale+shift) @ W2  (128 -> 40) -------
// block: 256 threads -> 128 rows; thread: 2 rows x 10 cols (strided c=colg+4j)
#define G2_ROWS 128
#define XS_LD 132   // padded: bank = (4*row + k) % 32, conflict-free-ish
#define W2_LD 132
__global__ __launch_bounds__(256) void gemm2(const float* __restrict__ hrelu,
                                             const float* __restrict__ W2,
                                             const float* __restrict__ scale,
                                             const float* __restrict__ shift,
                                             float* __restrict__ h2) {
    __shared__ float W2t[C_OUT * W2_LD];     // [c][k] transposed, ~21 KB
    __shared__ float Xs[G2_ROWS * XS_LD];    // ~67.6 KB

    for (int i = threadIdx.x; i < H_DIM * C_OUT; i += 256) {
        int k = i / C_OUT, c = i % C_OUT;
        W2t[c * W2_LD + k] = W2[i];
    }
    int base = blockIdx.x * G2_ROWS;
    for (int i = threadIdx.x; i < G2_ROWS * H_DIM / 4; i += 256) {
        int r = i >> 5;           // 32 float4 per row
        int k4 = (i & 31) * 4;
        int gr = base + r;
        if (gr >= N_NODES) gr = N_NODES - 1;
        float4 v  = *(const float4*)(hrelu + (size_t)gr * H_DIM + k4);
        float4 sc = *(const float4*)(scale + k4);
        float4 sh = *(const float4*)(shift + k4);
        float4 o  = {fmaf(v.x, sc.x, sh.x), fmaf(v.y, sc.y, sh.y),
                     fmaf(v.z, sc.z, sh.z), fmaf(v.w, sc.w, sh.w)};
        *(float4*)&Xs[r * XS_LD + k4] = o;
    }
    __syncthreads();

    int colg = threadIdx.x & 3;    // cols colg + 4j, j=0..9
    int rowg = threadIdx.x >> 2;   // rows rowg, rowg+64

    float acc0[10] = {}, acc1[10] = {};
    for (int k = 0; k < H_DIM; k += 4) {
        float4 xa = *(const float4*)&Xs[rowg * XS_LD + k];
        float4 xb = *(const float4*)&Xs[(rowg + 64) * XS_LD + k];
        #pragma unroll
        for (int j = 0; j < 10; ++j) {
            int c = colg + 4 * j;
            float4 wv = *(const float4*)&W2t[c * W2_LD + k];
            acc0[j] = fmaf(xa.x, wv.x, acc0[j]);
            acc0[j] = fmaf(xa.y, wv.y, acc0[j]);
            acc0[j] = fmaf(xa.z, wv.z, acc0[j]);
            acc0[j] = fmaf(xa.w, wv.w, acc0[j]);
            acc1[j] = fmaf(xb.x, wv.x, acc1[j]);
            acc1[j] = fmaf(xb.y, wv.y, acc1[j]);
            acc1[j] = fmaf(xb.z, wv.z, acc1[j]);
            acc1[j] = fmaf(xb.w, wv.w, acc1[j]);
        }
    }
    int gr0 = base + rowg, gr1 = base + rowg + 64;
    #pragma unroll
    for (int j = 0; j < 10; ++j) {
        int c = colg + 4 * j;
        if (gr0 < N_NODES) h2[(size_t)gr0 * C_OUT + c] = acc0[j];
        if (gr1 < N_NODES) h2[(size_t)gr1 * C_OUT + c] = acc1[j];
    }
}

// ---------------- scatter layer 2: out[dst] += h2[src]*norm (40 ch) -------
__global__ __launch_bounds__(256) void scatter2(const int* __restrict__ src,
                                                const int* __restrict__ dst,
                                                const float* __restrict__ dinv,
                                                const float* __restrict__ h2,
                                                float* __restrict__ out) {
    int gid = blockIdx.x * 256 + threadIdx.x;   // < 68M
    int e = gid / C_OUT;
    if (e >= N_EDGES + N_NODES) return;
    int c = gid - e * C_OUT;
    int s, d; float w;
    if (e < N_EDGES) {
        s = src[e]; d = dst[e];
        w = dinv[s] * dinv[d];
    } else {
        s = d = e - N_EDGES;
        float dv = dinv[s];
        w = dv * dv;
    }
    atomicAdd(&out[(size_t)d * C_OUT + c], h2[(size_t)s * C_OUT + c] * w);
}

// ---------------- + b2, log_softmax in place (wave per node) ----------------
__global__ __launch_bounds__(256) void logsoftmax(float* __restrict__ out,
                                                  const float* __restrict__ b2) {
    int node = blockIdx.x * 4 + (threadIdx.x >> 6);
    if (node >= N_NODES) return;
    int lane = threadIdx.x & 63;
    float* row = out + (size_t)node * C_OUT;
    float myv = 0.f;
    float v = -INFINITY;
    if (lane < C_OUT) { myv = row[lane] + b2[lane]; v = myv; }
    #pragma unroll
    for (int off = 32; off; off >>= 1) v = fmaxf(v, __shfl_xor(v, off));
    float ex = (lane < C_OUT) ? expf(myv - v) : 0.f;
    #pragma unroll
    for (int off = 32; off; off >>= 1) ex += __shfl_xor(ex, off);
    float lse = logf(ex) + v;
    if (lane < C_OUT) row[lane] = myv - lse;
}

// ---------------- launch ----------------
extern "C" void kernel_launch(void* const* d_in, const int* in_sizes, int n_in,
                              void* d_out, int out_size, void* d_ws, size_t ws_size,
                              hipStream_t stream) {
    const float* x     = (const float*)d_in[0];
    const int*   eidx  = (const int*)d_in[1];
    const float* W1    = (const float*)d_in[2];
    const float* b1    = (const float*)d_in[3];
    const float* gamma = (const float*)d_in[4];
    const float* beta  = (const float*)d_in[5];
    const float* W2    = (const float*)d_in[6];
    const float* b2    = (const float*)d_in[7];
    float* out = (float*)d_out;

    const int* src = eidx;            // edge_index[0]
    const int* dst = eidx + N_EDGES;  // edge_index[1]

    // workspace layout (floats)
    float* ws   = (float*)d_ws;
    float* deg  = ws;                               // N            (dinv in place)
    float* h1   = ws + 100000;                      // N*128  (later aliased by h2pre)
    float* agg1 = h1 + (size_t)N_NODES * H_DIM;     // N*128  (relu'd in place)
    float* stats = agg1 + (size_t)N_NODES * H_DIM;  // 512 floats
    float* sums = stats, *sumsq = stats + 128, *scale = stats + 256, *shift = stats + 384;
    float* h2pre = h1;                              // alias: h1 dead after scatter1

    size_t needed = (size_t)(100000 + 2 * N_NODES * H_DIM + 512) * 4;
    if (ws_size < needed) return;  // visible as validation failure, not a crash

    // per-call init (harness does not re-poison between replays)
    hipMemsetAsync(agg1, 0, (size_t)N_NODES * H_DIM * 4, stream);
    hipMemsetAsync(stats, 0, 512 * 4, stream);
    hipMemsetAsync(out, 0, (size_t)N_NODES * C_OUT * 4, stream);

    deg_init<<<(N_NODES + 255) / 256, 256, 0, stream>>>(deg);
    deg_count<<<(N_EDGES + 255) / 256, 256, 0, stream>>>(dst, deg);
    deg_rsqrt<<<(N_NODES + 255) / 256, 256, 0, stream>>>(deg);

    gemm1<<<(N_NODES + 63) / 64, 256, 0, stream>>>(x, W1, h1);

    scatter1<<<((N_EDGES + N_NODES) * 32) / 256, 256, 0, stream>>>(src, dst, deg, h1, agg1);

    relu_stats<<<1024, 256, 0, stream>>>(agg1, b1, sums, sumsq);
    bn_final<<<1, 128, 0, stream>>>(sums, sumsq, gamma, beta, scale, shift);

    gemm2<<<(N_NODES + G2_ROWS - 1) / G2_ROWS, 256, 0, stream>>>(agg1, W2, scale, shift, h2pre);

    scatter2<<<((size_t)(N_EDGES + N_NODES) * C_OUT + 255) / 256, 256, 0, stream>>>(src, dst, deg, h2pre, out);

    logsoftmax<<<(N_NODES + 3) / 4, 256, 0, stream>>>(out, b2);
}

// Round 2
// 569.961 us; speedup vs baseline: 5.9394x; 5.9394x over previous
//
#include <hip/hip_runtime.h>
#include <math.h>

#define N_NODES 100000
#define N_EDGES 1600000
#define F_IN 128
#define H_DIM 128
#define C_OUT 40
#define BN_EPS 1e-5f
#define NSEG (N_EDGES + N_NODES)
#define SCAN_T 512
#define SCAN_NB ((N_NODES + 1 + SCAN_T - 1) / SCAN_T)   // 196

// ---------------- CSR build ----------------
__global__ __launch_bounds__(256) void cnt_init(int* cnt) {
    int i = blockIdx.x * 256 + threadIdx.x;
    if (i < N_NODES) cnt[i] = 1;                 // self-loop
}

__global__ __launch_bounds__(256) void cnt_count(const int* __restrict__ dst,
                                                 int* __restrict__ cnt) {
    int e = blockIdx.x * 256 + threadIdx.x;
    if (e < N_EDGES) atomicAdd(&cnt[dst[e]], 1);
}

__global__ __launch_bounds__(256) void dinv_k(const int* __restrict__ cnt,
                                              float* __restrict__ dinv) {
    int i = blockIdx.x * 256 + threadIdx.x;
    if (i < N_NODES) dinv[i] = rsqrtf((float)cnt[i]);   // cnt >= 1
}

// exclusive scan of cnt[0..N-1] (element N treated as 0) -> rowoff[0..N]
__global__ __launch_bounds__(SCAN_T) void scan_block(const int* __restrict__ cnt,
                                                     int* __restrict__ rowoff,
                                                     int* __restrict__ bsum) {
    __shared__ int tmp[SCAN_T];
    int i = blockIdx.x * SCAN_T + threadIdx.x;
    int v = (i < N_NODES) ? cnt[i] : 0;
    tmp[threadIdx.x] = v;
    __syncthreads();
    for (int off = 1; off < SCAN_T; off <<= 1) {
        int t = (threadIdx.x >= off) ? tmp[threadIdx.x - off] : 0;
        __syncthreads();
        tmp[threadIdx.x] += t;
        __syncthreads();
    }
    if (i <= N_NODES) rowoff[i] = tmp[threadIdx.x] - v;   // exclusive
    if (threadIdx.x == SCAN_T - 1) bsum[blockIdx.x] = tmp[SCAN_T - 1];
}

__global__ void scan_bsum(int* bsum) {
    if (threadIdx.x == 0) {
        int acc = 0;
        for (int b = 0; b < SCAN_NB; ++b) { int v = bsum[b]; bsum[b] = acc; acc += v; }
    }
}

__global__ __launch_bounds__(SCAN_T) void scan_add(int* __restrict__ rowoff,
                                                   const int* __restrict__ bsum) {
    int i = blockIdx.x * SCAN_T + threadIdx.x;
    if (i <= N_NODES) rowoff[i] += bsum[blockIdx.x];
}

__global__ __launch_bounds__(256) void cursor_init(const int* __restrict__ rowoff,
                                                   int* __restrict__ cursor) {
    int i = blockIdx.x * 256 + threadIdx.x;
    if (i < N_NODES) cursor[i] = rowoff[i];
}

__global__ __launch_bounds__(256) void fill_self(int* __restrict__ cursor,
                                                 int* __restrict__ csr) {
    int i = blockIdx.x * 256 + threadIdx.x;
    if (i < N_NODES) { int pos = atomicAdd(&cursor[i], 1); csr[pos] = i; }
}

__global__ __launch_bounds__(256) void fill_edges(const int* __restrict__ src,
                                                  const int* __restrict__ dst,
                                                  int* __restrict__ cursor,
                                                  int* __restrict__ csr) {
    int e = blockIdx.x * 256 + threadIdx.x;
    if (e < N_EDGES) { int pos = atomicAdd(&cursor[dst[e]], 1); csr[pos] = src[e]; }
}

// ---------------- gather layer 1 over x: agg[n] = sum_s dinv[s]*dinv[n]*x[s]
// 32 threads per node (4 ch each), 8 nodes per block
__global__ __launch_bounds__(256) void gather_x(const int* __restrict__ rowoff,
                                                const int* __restrict__ csr,
                                                const float* __restrict__ dinv,
                                                const float* __restrict__ x,
                                                float* __restrict__ agg) {
    int node = blockIdx.x * 8 + (threadIdx.x >> 5);
    if (node >= N_NODES) return;
    int lane = (threadIdx.x & 31) * 4;
    int beg = rowoff[node], end = rowoff[node + 1];
    float dd = dinv[node];
    float4 a0 = {0, 0, 0, 0}, a1 = {0, 0, 0, 0};
    int e = beg;
    for (; e + 1 < end; e += 2) {
        int s0 = csr[e], s1 = csr[e + 1];
        float w0 = dinv[s0] * dd, w1 = dinv[s1] * dd;
        float4 v0 = *(const float4*)(x + (size_t)s0 * F_IN + lane);
        float4 v1 = *(const float4*)(x + (size_t)s1 * F_IN + lane);
        a0.x = fmaf(v0.x, w0, a0.x); a0.y = fmaf(v0.y, w0, a0.y);
        a0.z = fmaf(v0.z, w0, a0.z); a0.w = fmaf(v0.w, w0, a0.w);
        a1.x = fmaf(v1.x, w1, a1.x); a1.y = fmaf(v1.y, w1, a1.y);
        a1.z = fmaf(v1.z, w1, a1.z); a1.w = fmaf(v1.w, w1, a1.w);
    }
    if (e < end) {
        int s0 = csr[e];
        float w0 = dinv[s0] * dd;
        float4 v0 = *(const float4*)(x + (size_t)s0 * F_IN + lane);
        a0.x = fmaf(v0.x, w0, a0.x); a0.y = fmaf(v0.y, w0, a0.y);
        a0.z = fmaf(v0.z, w0, a0.z); a0.w = fmaf(v0.w, w0, a0.w);
    }
    float4 r = {a0.x + a1.x, a0.y + a1.y, a0.z + a1.z, a0.w + a1.w};
    *(float4*)(agg + (size_t)node * H_DIM + lane) = r;
}

// ---------------- GEMM1 in place: A <- relu(A@W1 + b1), + BN batch stats ----
// block: 256 threads -> 64 rows x 128 cols; thread: 4 rows x 8 cols
__global__ __launch_bounds__(256) void gemm1_fused(float* __restrict__ A,
                                                   const float* __restrict__ W,
                                                   const float* __restrict__ b1,
                                                   float* __restrict__ gsums,
                                                   float* __restrict__ gsumsq) {
    __shared__ float Ws[F_IN * H_DIM];   // 64 KB
    __shared__ float ls[H_DIM], lq[H_DIM];
    for (int i = threadIdx.x; i < F_IN * H_DIM / 4; i += 256)
        ((float4*)Ws)[i] = ((const float4*)W)[i];
    if (threadIdx.x < 128) ls[threadIdx.x] = 0.f;
    else lq[threadIdx.x - 128] = 0.f;
    __syncthreads();

    int ty = threadIdx.x >> 4;
    int tx = threadIdx.x & 15;
    int row0 = blockIdx.x * 64 + ty * 4;

    int r[4];
    #pragma unroll
    for (int i = 0; i < 4; ++i) {
        int rr = row0 + i;
        r[i] = rr < N_NODES ? rr : N_NODES - 1;   // clamped rows: garbage ok, discarded
    }

    float acc[4][8] = {};
    for (int k = 0; k < F_IN; k += 4) {
        float4 xv[4];
        #pragma unroll
        for (int i = 0; i < 4; ++i)
            xv[i] = *(const float4*)(A + (size_t)r[i] * F_IN + k);
        #pragma unroll
        for (int kk = 0; kk < 4; ++kk) {
            float4 w0 = *(const float4*)&Ws[(k + kk) * H_DIM + tx * 4];
            float4 w1 = *(const float4*)&Ws[(k + kk) * H_DIM + 64 + tx * 4];
            #pragma unroll
            for (int i = 0; i < 4; ++i) {
                float xs = (&xv[i].x)[kk];
                acc[i][0] = fmaf(xs, w0.x, acc[i][0]);
                acc[i][1] = fmaf(xs, w0.y, acc[i][1]);
                acc[i][2] = fmaf(xs, w0.z, acc[i][2]);
                acc[i][3] = fmaf(xs, w0.w, acc[i][3]);
                acc[i][4] = fmaf(xs, w1.x, acc[i][4]);
                acc[i][5] = fmaf(xs, w1.y, acc[i][5]);
                acc[i][6] = fmaf(xs, w1.z, acc[i][6]);
                acc[i][7] = fmaf(xs, w1.w, acc[i][7]);
            }
        }
    }

    float4 b0 = *(const float4*)(b1 + tx * 4);
    float4 b1v = *(const float4*)(b1 + 64 + tx * 4);
    float cs[8] = {}, cq[8] = {};
    #pragma unroll
    for (int i = 0; i < 4; ++i) {
        int rr = row0 + i;
        if (rr < N_NODES) {
            float o[8];
            o[0] = fmaxf(acc[i][0] + b0.x, 0.f);
            o[1] = fmaxf(acc[i][1] + b0.y, 0.f);
            o[2] = fmaxf(acc[i][2] + b0.z, 0.f);
            o[3] = fmaxf(acc[i][3] + b0.w, 0.f);
            o[4] = fmaxf(acc[i][4] + b1v.x, 0.f);
            o[5] = fmaxf(acc[i][5] + b1v.y, 0.f);
            o[6] = fmaxf(acc[i][6] + b1v.z, 0.f);
            o[7] = fmaxf(acc[i][7] + b1v.w, 0.f);
            float4 s0 = {o[0], o[1], o[2], o[3]};
            float4 s1 = {o[4], o[5], o[6], o[7]};
            *(float4*)(A + (size_t)rr * H_DIM + tx * 4) = s0;
            *(float4*)(A + (size_t)rr * H_DIM + 64 + tx * 4) = s1;
            #pragma unroll
            for (int j = 0; j < 8; ++j) { cs[j] += o[j]; cq[j] += o[j] * o[j]; }
        }
    }
    #pragma unroll
    for (int j = 0; j < 4; ++j) {
        atomicAdd(&ls[tx * 4 + j], cs[j]);
        atomicAdd(&lq[tx * 4 + j], cq[j]);
        atomicAdd(&ls[64 + tx * 4 + j], cs[4 + j]);
        atomicAdd(&lq[64 + tx * 4 + j], cq[4 + j]);
    }
    __syncthreads();
    if (threadIdx.x < 128) atomicAdd(&gsums[threadIdx.x], ls[threadIdx.x]);
    else atomicAdd(&gsumsq[threadIdx.x - 128], lq[threadIdx.x - 128]);
}

__global__ void bn_final(const float* __restrict__ sums,
                         const float* __restrict__ sumsq,
                         const float* __restrict__ gamma,
                         const float* __restrict__ beta,
                         float* __restrict__ scale,
                         float* __restrict__ shift) {
    int c = threadIdx.x;
    if (c < H_DIM) {
        const float invn = 1.0f / (float)N_NODES;
        float mean = sums[c] * invn;
        float var = sumsq[c] * invn - mean * mean;
        float sc = gamma[c] * rsqrtf(var + BN_EPS);
        scale[c] = sc;
        shift[c] = beta[c] - mean * sc;
    }
}

// ---------------- GEMM2: h2 = (hrelu*scale+shift) @ W2  (128 -> 40) -------
#define G2_ROWS 128
#define XS_LD 132
#define W2_LD 132
__global__ __launch_bounds__(256) void gemm2(const float* __restrict__ hrelu,
                                             const float* __restrict__ W2,
                                             const float* __restrict__ scale,
                                             const float* __restrict__ shift,
                                             float* __restrict__ h2) {
    __shared__ float W2t[C_OUT * W2_LD];
    __shared__ float Xs[G2_ROWS * XS_LD];

    for (int i = threadIdx.x; i < H_DIM * C_OUT; i += 256) {
        int k = i / C_OUT, c = i % C_OUT;
        W2t[c * W2_LD + k] = W2[i];
    }
    int base = blockIdx.x * G2_ROWS;
    for (int i = threadIdx.x; i < G2_ROWS * H_DIM / 4; i += 256) {
        int r = i >> 5;
        int k4 = (i & 31) * 4;
        int gr = base + r;
        if (gr >= N_NODES) gr = N_NODES - 1;
        float4 v  = *(const float4*)(hrelu + (size_t)gr * H_DIM + k4);
        float4 sc = *(const float4*)(scale + k4);
        float4 sh = *(const float4*)(shift + k4);
        float4 o  = {fmaf(v.x, sc.x, sh.x), fmaf(v.y, sc.y, sh.y),
                     fmaf(v.z, sc.z, sh.z), fmaf(v.w, sc.w, sh.w)};
        *(float4*)&Xs[r * XS_LD + k4] = o;
    }
    __syncthreads();

    int colg = threadIdx.x & 3;
    int rowg = threadIdx.x >> 2;

    float acc0[10] = {}, acc1[10] = {};
    for (int k = 0; k < H_DIM; k += 4) {
        float4 xa = *(const float4*)&Xs[rowg * XS_LD + k];
        float4 xb = *(const float4*)&Xs[(rowg + 64) * XS_LD + k];
        #pragma unroll
        for (int j = 0; j < 10; ++j) {
            int c = colg + 4 * j;
            float4 wv = *(const float4*)&W2t[c * W2_LD + k];
            acc0[j] = fmaf(xa.x, wv.x, acc0[j]);
            acc0[j] = fmaf(xa.y, wv.y, acc0[j]);
            acc0[j] = fmaf(xa.z, wv.z, acc0[j]);
            acc0[j] = fmaf(xa.w, wv.w, acc0[j]);
            acc1[j] = fmaf(xb.x, wv.x, acc1[j]);
            acc1[j] = fmaf(xb.y, wv.y, acc1[j]);
            acc1[j] = fmaf(xb.z, wv.z, acc1[j]);
            acc1[j] = fmaf(xb.w, wv.w, acc1[j]);
        }
    }
    int gr0 = base + rowg, gr1 = base + rowg + 64;
    #pragma unroll
    for (int j = 0; j < 10; ++j) {
        int c = colg + 4 * j;
        if (gr0 < N_NODES) h2[(size_t)gr0 * C_OUT + c] = acc0[j];
        if (gr1 < N_NODES) h2[(size_t)gr1 * C_OUT + c] = acc1[j];
    }
}

// ---------------- gather layer 2: out[n] = sum_s w*h2[s]  (40 ch) ----------
// 16 threads per node (q<10 active, float4 each), 16 nodes per block
__global__ __launch_bounds__(256) void gather2(const int* __restrict__ rowoff,
                                               const int* __restrict__ csr,
                                               const float* __restrict__ dinv,
                                               const float* __restrict__ h2,
                                               float* __restrict__ out) {
    int node = blockIdx.x * 16 + (threadIdx.x >> 4);
    if (node >= N_NODES) return;
    int q = threadIdx.x & 15;
    int beg = rowoff[node], end = rowoff[node + 1];
    float dd = dinv[node];
    float4 a0 = {0, 0, 0, 0}, a1 = {0, 0, 0, 0};
    int e = beg;
    for (; e + 1 < end; e += 2) {
        int s0 = csr[e], s1 = csr[e + 1];
        float w0 = dinv[s0] * dd, w1 = dinv[s1] * dd;
        if (q < 10) {
            float4 v0 = *(const float4*)(h2 + (size_t)s0 * C_OUT + q * 4);
            float4 v1 = *(const float4*)(h2 + (size_t)s1 * C_OUT + q * 4);
            a0.x = fmaf(v0.x, w0, a0.x); a0.y = fmaf(v0.y, w0, a0.y);
            a0.z = fmaf(v0.z, w0, a0.z); a0.w = fmaf(v0.w, w0, a0.w);
            a1.x = fmaf(v1.x, w1, a1.x); a1.y = fmaf(v1.y, w1, a1.y);
            a1.z = fmaf(v1.z, w1, a1.z); a1.w = fmaf(v1.w, w1, a1.w);
        }
    }
    if (e < end) {
        int s0 = csr[e];
        float w0 = dinv[s0] * dd;
        if (q < 10) {
            float4 v0 = *(const float4*)(h2 + (size_t)s0 * C_OUT + q * 4);
            a0.x = fmaf(v0.x, w0, a0.x); a0.y = fmaf(v0.y, w0, a0.y);
            a0.z = fmaf(v0.z, w0, a0.z); a0.w = fmaf(v0.w, w0, a0.w);
        }
    }
    if (q < 10) {
        float4 r = {a0.x + a1.x, a0.y + a1.y, a0.z + a1.z, a0.w + a1.w};
        *(float4*)(out + (size_t)node * C_OUT + q * 4) = r;
    }
}

// ---------------- + b2, log_softmax in place (wave per node) ----------------
__global__ __launch_bounds__(256) void logsoftmax(float* __restrict__ out,
                                                  const float* __restrict__ b2) {
    int node = blockIdx.x * 4 + (threadIdx.x >> 6);
    if (node >= N_NODES) return;
    int lane = threadIdx.x & 63;
    float* row = out + (size_t)node * C_OUT;
    float myv = 0.f;
    float v = -INFINITY;
    if (lane < C_OUT) { myv = row[lane] + b2[lane]; v = myv; }
    #pragma unroll
    for (int off = 32; off; off >>= 1) v = fmaxf(v, __shfl_xor(v, off));
    float ex = (lane < C_OUT) ? expf(myv - v) : 0.f;
    #pragma unroll
    for (int off = 32; off; off >>= 1) ex += __shfl_xor(ex, off);
    float lse = logf(ex) + v;
    if (lane < C_OUT) row[lane] = myv - lse;
}

// ---------------- launch ----------------
extern "C" void kernel_launch(void* const* d_in, const int* in_sizes, int n_in,
                              void* d_out, int out_size, void* d_ws, size_t ws_size,
                              hipStream_t stream) {
    const float* x     = (const float*)d_in[0];
    const int*   eidx  = (const int*)d_in[1];
    const float* W1    = (const float*)d_in[2];
    const float* b1    = (const float*)d_in[3];
    const float* gamma = (const float*)d_in[4];
    const float* beta  = (const float*)d_in[5];
    const float* W2    = (const float*)d_in[6];
    const float* b2    = (const float*)d_in[7];
    float* out = (float*)d_out;

    const int* src = eidx;
    const int* dst = eidx + N_EDGES;

    // workspace layout (4B units)
    float* ws = (float*)d_ws;
    int*   cnt    = (int*)ws;                 // N ints; reused as cursor after scan
    float* dinv   = ws + 100000;              // N
    int*   rowoff = (int*)(ws + 200000);      // N+1
    int*   bsum   = (int*)(ws + 300032);      // SCAN_NB
    int*   csr    = (int*)(ws + 301056);      // NSEG = 1.7M
    float* agg    = ws + 2001152;             // N*128 (aggx -> relu'd h, in place)
    float* h2     = ws + 14801152;            // N*40
    float* stats  = ws + 18801152;            // 512
    float* sums = stats, *sumsq = stats + 128, *scale = stats + 256, *shift = stats + 384;
    int*   cursor = cnt;

    size_t needed = (size_t)(18801152 + 512) * 4;
    if (ws_size < needed) return;

    hipMemsetAsync(stats, 0, 512 * 4, stream);

    // CSR build
    cnt_init<<<(N_NODES + 255) / 256, 256, 0, stream>>>(cnt);
    cnt_count<<<(N_EDGES + 255) / 256, 256, 0, stream>>>(dst, cnt);
    dinv_k<<<(N_NODES + 255) / 256, 256, 0, stream>>>(cnt, dinv);
    scan_block<<<SCAN_NB, SCAN_T, 0, stream>>>(cnt, rowoff, bsum);
    scan_bsum<<<1, 64, 0, stream>>>(bsum);
    scan_add<<<SCAN_NB, SCAN_T, 0, stream>>>(rowoff, bsum);
    cursor_init<<<(N_NODES + 255) / 256, 256, 0, stream>>>(rowoff, cursor);
    fill_self<<<(N_NODES + 255) / 256, 256, 0, stream>>>(cursor, csr);
    fill_edges<<<(N_EDGES + 255) / 256, 256, 0, stream>>>(src, dst, cursor, csr);

    // layer 1: aggregate x, then in-place GEMM + bias + relu + BN stats
    gather_x<<<N_NODES / 8, 256, 0, stream>>>(rowoff, csr, dinv, x, agg);
    gemm1_fused<<<(N_NODES + 63) / 64, 256, 0, stream>>>(agg, W1, b1, sums, sumsq);
    bn_final<<<1, 128, 0, stream>>>(sums, sumsq, gamma, beta, scale, shift);

    // layer 2: BN-affine folded into GEMM2 load, then gather, then log_softmax
    gemm2<<<(N_NODES + G2_ROWS - 1) / G2_ROWS, 256, 0, stream>>>(agg, W2, scale, shift, h2);
    gather2<<<(N_NODES + 15) / 16, 256, 0, stream>>>(rowoff, csr, dinv, h2, out);
    logsoftmax<<<(N_NODES + 3) / 4, 256, 0, stream>>>(out, b2);
}

// Round 3
// 401.691 us; speedup vs baseline: 8.4274x; 1.4189x over previous
//
#include <hip/hip_runtime.h>
#include <math.h>

#define N_NODES 100000
#define N_EDGES 1600000
#define F_IN 128
#define H_DIM 128
#define C_OUT 40
#define BN_EPS 1e-5f
#define NSEG (N_EDGES + N_NODES)
#define SCAN_T 512
#define SCAN_NB ((N_NODES + 1 + SCAN_T - 1) / SCAN_T)   // 196

typedef unsigned short u16;
typedef unsigned int u32;

__device__ __forceinline__ u16 f2bf(float f) {              // RNE
    u32 u = __float_as_uint(f);
    u += 0x7FFFu + ((u >> 16) & 1u);
    return (u16)(u >> 16);
}
__device__ __forceinline__ float bf2f(u16 h) {
    return __uint_as_float(((u32)h) << 16);
}

// ---------------- CSR build ----------------
__global__ __launch_bounds__(256) void cnt_init(int* cnt) {
    int i = blockIdx.x * 256 + threadIdx.x;
    if (i < N_NODES) cnt[i] = 1;                 // self-loop occupies slot 0
}

// counts AND records each edge's arrival position within its dst bucket
__global__ __launch_bounds__(256) void cnt_count(const int* __restrict__ dst,
                                                 int* __restrict__ cnt,
                                                 int* __restrict__ aux) {
    int e = blockIdx.x * 256 + threadIdx.x;
    if (e < N_EDGES) aux[e] = atomicAdd(&cnt[dst[e]], 1);   // returns >= 1
}

// exclusive scan of cnt[0..N-1] -> rowoff[0..N]
__global__ __launch_bounds__(SCAN_T) void scan_block(const int* __restrict__ cnt,
                                                     int* __restrict__ rowoff,
                                                     int* __restrict__ bsum) {
    __shared__ int tmp[SCAN_T];
    int i = blockIdx.x * SCAN_T + threadIdx.x;
    int v = (i < N_NODES) ? cnt[i] : 0;
    tmp[threadIdx.x] = v;
    __syncthreads();
    for (int off = 1; off < SCAN_T; off <<= 1) {
        int t = (threadIdx.x >= off) ? tmp[threadIdx.x - off] : 0;
        __syncthreads();
        tmp[threadIdx.x] += t;
        __syncthreads();
    }
    if (i <= N_NODES) rowoff[i] = tmp[threadIdx.x] - v;   // exclusive
    if (threadIdx.x == SCAN_T - 1) bsum[blockIdx.x] = tmp[SCAN_T - 1];
}

__global__ void scan_bsum(int* bsum) {
    if (threadIdx.x == 0) {
        int acc = 0;
        for (int b = 0; b < SCAN_NB; ++b) { int v = bsum[b]; bsum[b] = acc; acc += v; }
    }
}

__global__ __launch_bounds__(SCAN_T) void scan_add(int* __restrict__ rowoff,
                                                   const int* __restrict__ bsum) {
    int i = blockIdx.x * SCAN_T + threadIdx.x;
    if (i <= N_NODES) rowoff[i] += bsum[blockIdx.x];
}

// dinv = rsqrt(deg); also place the self-loop at slot 0 of each row
__global__ __launch_bounds__(256) void dinv_self(const int* __restrict__ cnt,
                                                 const int* __restrict__ rowoff,
                                                 float* __restrict__ dinv,
                                                 int* __restrict__ csr) {
    int i = blockIdx.x * 256 + threadIdx.x;
    if (i < N_NODES) {
        dinv[i] = rsqrtf((float)cnt[i]);
        csr[rowoff[i]] = i;
    }
}

// atomic-free scatter of edge sources into csr
__global__ __launch_bounds__(256) void fill_edges(const int* __restrict__ src,
                                                  const int* __restrict__ dst,
                                                  const int* __restrict__ rowoff,
                                                  const int* __restrict__ aux,
                                                  int* __restrict__ csr) {
    int e = blockIdx.x * 256 + threadIdx.x;
    if (e < N_EDGES) csr[rowoff[dst[e]] + aux[e]] = src[e];
}

// ---------------- x -> bf16 (RNE) ----------------
__global__ __launch_bounds__(256) void xconvert(const float* __restrict__ x,
                                                u16* __restrict__ xb) {
    int i = blockIdx.x * 256 + threadIdx.x;      // exactly 3.2M threads
    float4 v = ((const float4*)x)[i];
    ushort4 o;
    o.x = f2bf(v.x); o.y = f2bf(v.y); o.z = f2bf(v.z); o.w = f2bf(v.w);
    ((ushort4*)xb)[i] = o;
}

// ---------------- gather layer 1 over bf16 x ----------------
// 32 threads per node (4 ch each), 8 nodes per block
__global__ __launch_bounds__(256) void gather_x(const int* __restrict__ rowoff,
                                                const int* __restrict__ csr,
                                                const float* __restrict__ dinv,
                                                const u16* __restrict__ xb,
                                                float* __restrict__ agg) {
    int node = blockIdx.x * 8 + (threadIdx.x >> 5);      // grid exact: N%8==0
    int lane4 = (threadIdx.x & 31) * 4;
    int beg = rowoff[node], end = rowoff[node + 1];
    float dd = dinv[node];
    float4 a0 = {0, 0, 0, 0}, a1 = {0, 0, 0, 0};
    int e = beg;
    for (; e + 1 < end; e += 2) {
        int s0 = csr[e], s1 = csr[e + 1];
        float w0 = dinv[s0] * dd, w1 = dinv[s1] * dd;
        ushort4 v0 = *(const ushort4*)(xb + (size_t)s0 * F_IN + lane4);
        ushort4 v1 = *(const ushort4*)(xb + (size_t)s1 * F_IN + lane4);
        a0.x = fmaf(bf2f(v0.x), w0, a0.x); a0.y = fmaf(bf2f(v0.y), w0, a0.y);
        a0.z = fmaf(bf2f(v0.z), w0, a0.z); a0.w = fmaf(bf2f(v0.w), w0, a0.w);
        a1.x = fmaf(bf2f(v1.x), w1, a1.x); a1.y = fmaf(bf2f(v1.y), w1, a1.y);
        a1.z = fmaf(bf2f(v1.z), w1, a1.z); a1.w = fmaf(bf2f(v1.w), w1, a1.w);
    }
    if (e < end) {
        int s0 = csr[e];
        float w0 = dinv[s0] * dd;
        ushort4 v0 = *(const ushort4*)(xb + (size_t)s0 * F_IN + lane4);
        a0.x = fmaf(bf2f(v0.x), w0, a0.x); a0.y = fmaf(bf2f(v0.y), w0, a0.y);
        a0.z = fmaf(bf2f(v0.z), w0, a0.z); a0.w = fmaf(bf2f(v0.w), w0, a0.w);
    }
    float4 r = {a0.x + a1.x, a0.y + a1.y, a0.z + a1.z, a0.w + a1.w};
    *(float4*)(agg + (size_t)node * H_DIM + lane4) = r;
}

// ---------------- GEMM1 in place: A <- relu(A@W1 + b1), + BN batch stats ----
__global__ __launch_bounds__(256) void gemm1_fused(float* __restrict__ A,
                                                   const float* __restrict__ W,
                                                   const float* __restrict__ b1,
                                                   float* __restrict__ gsums,
                                                   float* __restrict__ gsumsq) {
    __shared__ float Ws[F_IN * H_DIM];   // 64 KB
    __shared__ float ls[H_DIM], lq[H_DIM];
    for (int i = threadIdx.x; i < F_IN * H_DIM / 4; i += 256)
        ((float4*)Ws)[i] = ((const float4*)W)[i];
    if (threadIdx.x < 128) ls[threadIdx.x] = 0.f;
    else lq[threadIdx.x - 128] = 0.f;
    __syncthreads();

    int ty = threadIdx.x >> 4;
    int tx = threadIdx.x & 15;
    int row0 = blockIdx.x * 64 + ty * 4;

    int r[4];
    #pragma unroll
    for (int i = 0; i < 4; ++i) {
        int rr = row0 + i;
        r[i] = rr < N_NODES ? rr : N_NODES - 1;   // clamped rows discarded below
    }

    float acc[4][8] = {};
    for (int k = 0; k < F_IN; k += 4) {
        float4 xv[4];
        #pragma unroll
        for (int i = 0; i < 4; ++i)
            xv[i] = *(const float4*)(A + (size_t)r[i] * F_IN + k);
        #pragma unroll
        for (int kk = 0; kk < 4; ++kk) {
            float4 w0 = *(const float4*)&Ws[(k + kk) * H_DIM + tx * 4];
            float4 w1 = *(const float4*)&Ws[(k + kk) * H_DIM + 64 + tx * 4];
            #pragma unroll
            for (int i = 0; i < 4; ++i) {
                float xs = (&xv[i].x)[kk];
                acc[i][0] = fmaf(xs, w0.x, acc[i][0]);
                acc[i][1] = fmaf(xs, w0.y, acc[i][1]);
                acc[i][2] = fmaf(xs, w0.z, acc[i][2]);
                acc[i][3] = fmaf(xs, w0.w, acc[i][3]);
                acc[i][4] = fmaf(xs, w1.x, acc[i][4]);
                acc[i][5] = fmaf(xs, w1.y, acc[i][5]);
                acc[i][6] = fmaf(xs, w1.z, acc[i][6]);
                acc[i][7] = fmaf(xs, w1.w, acc[i][7]);
            }
        }
    }

    float4 b0 = *(const float4*)(b1 + tx * 4);
    float4 b1v = *(const float4*)(b1 + 64 + tx * 4);
    float cs[8] = {}, cq[8] = {};
    #pragma unroll
    for (int i = 0; i < 4; ++i) {
        int rr = row0 + i;
        if (rr < N_NODES) {
            float o[8];
            o[0] = fmaxf(acc[i][0] + b0.x, 0.f);
            o[1] = fmaxf(acc[i][1] + b0.y, 0.f);
            o[2] = fmaxf(acc[i][2] + b0.z, 0.f);
            o[3] = fmaxf(acc[i][3] + b0.w, 0.f);
            o[4] = fmaxf(acc[i][4] + b1v.x, 0.f);
            o[5] = fmaxf(acc[i][5] + b1v.y, 0.f);
            o[6] = fmaxf(acc[i][6] + b1v.z, 0.f);
            o[7] = fmaxf(acc[i][7] + b1v.w, 0.f);
            float4 s0 = {o[0], o[1], o[2], o[3]};
            float4 s1 = {o[4], o[5], o[6], o[7]};
            *(float4*)(A + (size_t)rr * H_DIM + tx * 4) = s0;
            *(float4*)(A + (size_t)rr * H_DIM + 64 + tx * 4) = s1;
            #pragma unroll
            for (int j = 0; j < 8; ++j) { cs[j] += o[j]; cq[j] += o[j] * o[j]; }
        }
    }
    #pragma unroll
    for (int j = 0; j < 4; ++j) {
        atomicAdd(&ls[tx * 4 + j], cs[j]);
        atomicAdd(&lq[tx * 4 + j], cq[j]);
        atomicAdd(&ls[64 + tx * 4 + j], cs[4 + j]);
        atomicAdd(&lq[64 + tx * 4 + j], cq[4 + j]);
    }
    __syncthreads();
    if (threadIdx.x < 128) atomicAdd(&gsums[threadIdx.x], ls[threadIdx.x]);
    else atomicAdd(&gsumsq[threadIdx.x - 128], lq[threadIdx.x - 128]);
}

__global__ void bn_final(const float* __restrict__ sums,
                         const float* __restrict__ sumsq,
                         const float* __restrict__ gamma,
                         const float* __restrict__ beta,
                         float* __restrict__ scale,
                         float* __restrict__ shift) {
    int c = threadIdx.x;
    if (c < H_DIM) {
        const float invn = 1.0f / (float)N_NODES;
        float mean = sums[c] * invn;
        float var = sumsq[c] * invn - mean * mean;
        float sc = gamma[c] * rsqrtf(var + BN_EPS);
        scale[c] = sc;
        shift[c] = beta[c] - mean * sc;
    }
}

// ---------------- GEMM2: h2b(bf16) = (hrelu*scale+shift) @ W2  (128->40) ----
#define G2_ROWS 128
#define XS_LD 132
#define W2_LD 132
__global__ __launch_bounds__(256) void gemm2(const float* __restrict__ hrelu,
                                             const float* __restrict__ W2,
                                             const float* __restrict__ scale,
                                             const float* __restrict__ shift,
                                             u16* __restrict__ h2b) {
    __shared__ float W2t[C_OUT * W2_LD];
    __shared__ float Xs[G2_ROWS * XS_LD];

    for (int i = threadIdx.x; i < H_DIM * C_OUT; i += 256) {
        int k = i / C_OUT, c = i % C_OUT;
        W2t[c * W2_LD + k] = W2[i];
    }
    int base = blockIdx.x * G2_ROWS;
    for (int i = threadIdx.x; i < G2_ROWS * H_DIM / 4; i += 256) {
        int r = i >> 5;
        int k4 = (i & 31) * 4;
        int gr = base + r;
        if (gr >= N_NODES) gr = N_NODES - 1;
        float4 v  = *(const float4*)(hrelu + (size_t)gr * H_DIM + k4);
        float4 sc = *(const float4*)(scale + k4);
        float4 sh = *(const float4*)(shift + k4);
        float4 o  = {fmaf(v.x, sc.x, sh.x), fmaf(v.y, sc.y, sh.y),
                     fmaf(v.z, sc.z, sh.z), fmaf(v.w, sc.w, sh.w)};
        *(float4*)&Xs[r * XS_LD + k4] = o;
    }
    __syncthreads();

    int colg = threadIdx.x & 3;    // cols colg*10 + j, j=0..9 (contiguous per thread)
    int rowg = threadIdx.x >> 2;

    float acc0[10] = {}, acc1[10] = {};
    for (int k = 0; k < H_DIM; k += 4) {
        float4 xa = *(const float4*)&Xs[rowg * XS_LD + k];
        float4 xb = *(const float4*)&Xs[(rowg + 64) * XS_LD + k];
        #pragma unroll
        for (int j = 0; j < 10; ++j) {
            int c = colg * 10 + j;
            float4 wv = *(const float4*)&W2t[c * W2_LD + k];
            acc0[j] = fmaf(xa.x, wv.x, acc0[j]);
            acc0[j] = fmaf(xa.y, wv.y, acc0[j]);
            acc0[j] = fmaf(xa.z, wv.z, acc0[j]);
            acc0[j] = fmaf(xa.w, wv.w, acc0[j]);
            acc1[j] = fmaf(xb.x, wv.x, acc1[j]);
            acc1[j] = fmaf(xb.y, wv.y, acc1[j]);
            acc1[j] = fmaf(xb.z, wv.z, acc1[j]);
            acc1[j] = fmaf(xb.w, wv.w, acc1[j]);
        }
    }
    int gr0 = base + rowg, gr1 = base + rowg + 64;
    if (gr0 < N_NODES) {
        u16* p = h2b + (size_t)gr0 * C_OUT + colg * 10;
        #pragma unroll
        for (int t = 0; t < 5; ++t) {
            u32 v = (u32)f2bf(acc0[2 * t]) | ((u32)f2bf(acc0[2 * t + 1]) << 16);
            *(u32*)(p + 2 * t) = v;
        }
    }
    if (gr1 < N_NODES) {
        u16* p = h2b + (size_t)gr1 * C_OUT + colg * 10;
        #pragma unroll
        for (int t = 0; t < 5; ++t) {
            u32 v = (u32)f2bf(acc1[2 * t]) | ((u32)f2bf(acc1[2 * t + 1]) << 16);
            *(u32*)(p + 2 * t) = v;
        }
    }
}

// ------- gather layer 2 (bf16) + b2 + log_softmax fused, 16 lanes/node -------
__global__ __launch_bounds__(256) void gather2_fused(const int* __restrict__ rowoff,
                                                     const int* __restrict__ csr,
                                                     const float* __restrict__ dinv,
                                                     const u16* __restrict__ h2b,
                                                     const float* __restrict__ b2,
                                                     float* __restrict__ out) {
    int node = blockIdx.x * 16 + (threadIdx.x >> 4);     // grid exact: N%16==0
    int q = threadIdx.x & 15;
    int beg = rowoff[node], end = rowoff[node + 1];
    float dd = dinv[node];
    float4 a0 = {0, 0, 0, 0}, a1 = {0, 0, 0, 0};
    int e = beg;
    for (; e + 1 < end; e += 2) {
        int s0 = csr[e], s1 = csr[e + 1];
        float w0 = dinv[s0] * dd, w1 = dinv[s1] * dd;
        if (q < 10) {
            ushort4 v0 = *(const ushort4*)(h2b + (size_t)s0 * C_OUT + q * 4);
            ushort4 v1 = *(const ushort4*)(h2b + (size_t)s1 * C_OUT + q * 4);
            a0.x = fmaf(bf2f(v0.x), w0, a0.x); a0.y = fmaf(bf2f(v0.y), w0, a0.y);
            a0.z = fmaf(bf2f(v0.z), w0, a0.z); a0.w = fmaf(bf2f(v0.w), w0, a0.w);
            a1.x = fmaf(bf2f(v1.x), w1, a1.x); a1.y = fmaf(bf2f(v1.y), w1, a1.y);
            a1.z = fmaf(bf2f(v1.z), w1, a1.z); a1.w = fmaf(bf2f(v1.w), w1, a1.w);
        }
    }
    if (e < end) {
        int s0 = csr[e];
        float w0 = dinv[s0] * dd;
        if (q < 10) {
            ushort4 v0 = *(const ushort4*)(h2b + (size_t)s0 * C_OUT + q * 4);
            a0.x = fmaf(bf2f(v0.x), w0, a0.x); a0.y = fmaf(bf2f(v0.y), w0, a0.y);
            a0.z = fmaf(bf2f(v0.z), w0, a0.z); a0.w = fmaf(bf2f(v0.w), w0, a0.w);
        }
    }
    float4 r = {a0.x + a1.x, a0.y + a1.y, a0.z + a1.z, a0.w + a1.w};
    float m = -INFINITY;
    if (q < 10) {
        float4 bv = *(const float4*)(b2 + q * 4);
        r.x += bv.x; r.y += bv.y; r.z += bv.z; r.w += bv.w;
        m = fmaxf(fmaxf(r.x, r.y), fmaxf(r.z, r.w));
    }
    #pragma unroll
    for (int off = 1; off < 16; off <<= 1) m = fmaxf(m, __shfl_xor(m, off, 16));
    float ex = 0.f;
    if (q < 10)
        ex = expf(r.x - m) + expf(r.y - m) + expf(r.z - m) + expf(r.w - m);
    #pragma unroll
    for (int off = 1; off < 16; off <<= 1) ex += __shfl_xor(ex, off, 16);
    float lse = logf(ex) + m;
    if (q < 10) {
        float4 o = {r.x - lse, r.y - lse, r.z - lse, r.w - lse};
        *(float4*)(out + (size_t)node * C_OUT + q * 4) = o;
    }
}

// ---------------- launch ----------------
extern "C" void kernel_launch(void* const* d_in, const int* in_sizes, int n_in,
                              void* d_out, int out_size, void* d_ws, size_t ws_size,
                              hipStream_t stream) {
    const float* x     = (const float*)d_in[0];
    const int*   eidx  = (const int*)d_in[1];
    const float* W1    = (const float*)d_in[2];
    const float* b1    = (const float*)d_in[3];
    const float* gamma = (const float*)d_in[4];
    const float* beta  = (const float*)d_in[5];
    const float* W2    = (const float*)d_in[6];
    const float* b2    = (const float*)d_in[7];
    float* out = (float*)d_out;

    const int* src = eidx;
    const int* dst = eidx + N_EDGES;

    // workspace layout (4B units)
    float* ws = (float*)d_ws;
    int*   cnt    = (int*)ws;                  // N
    float* dinv   = ws + 100000;               // N
    int*   rowoff = (int*)(ws + 200000);       // N+1
    int*   bsum   = (int*)(ws + 300032);       // SCAN_NB
    int*   aux    = (int*)(ws + 301056);       // E
    int*   csr    = (int*)(ws + 1901056);      // NSEG
    u16*   xb     = (u16*)(ws + 3601056);      // N*128 bf16
    float* agg    = ws + 10001056;             // N*128 f32 (in-place relu'd h)
    u16*   h2b    = (u16*)(ws + 22801056);     // N*40 bf16
    float* stats  = ws + 24801056;             // 512
    float* sums = stats, *sumsq = stats + 128, *scale = stats + 256, *shift = stats + 384;

    size_t needed = (size_t)(24801056 + 512) * 4;
    if (ws_size < needed) return;

    hipMemsetAsync(stats, 0, 512 * 4, stream);

    // CSR build (atomic-free fill)
    cnt_init<<<(N_NODES + 255) / 256, 256, 0, stream>>>(cnt);
    cnt_count<<<(N_EDGES + 255) / 256, 256, 0, stream>>>(dst, cnt, aux);
    scan_block<<<SCAN_NB, SCAN_T, 0, stream>>>(cnt, rowoff, bsum);
    scan_bsum<<<1, 64, 0, stream>>>(bsum);
    scan_add<<<SCAN_NB, SCAN_T, 0, stream>>>(rowoff, bsum);
    dinv_self<<<(N_NODES + 255) / 256, 256, 0, stream>>>(cnt, rowoff, dinv, csr);
    fill_edges<<<(N_EDGES + 255) / 256, 256, 0, stream>>>(src, dst, rowoff, aux, csr);

    // layer 1
    xconvert<<<N_NODES * F_IN / 4 / 256, 256, 0, stream>>>(x, xb);
    gather_x<<<N_NODES / 8, 256, 0, stream>>>(rowoff, csr, dinv, xb, agg);
    gemm1_fused<<<(N_NODES + 63) / 64, 256, 0, stream>>>(agg, W1, b1, sums, sumsq);
    bn_final<<<1, 128, 0, stream>>>(sums, sumsq, gamma, beta, scale, shift);

    // layer 2
    gemm2<<<(N_NODES + G2_ROWS - 1) / G2_ROWS, 256, 0, stream>>>(agg, W2, scale, shift, h2b);
    gather2_fused<<<N_NODES / 16, 256, 0, stream>>>(rowoff, csr, dinv, h2b, b2, out);
}

// Round 4
// 393.497 us; speedup vs baseline: 8.6029x; 1.0208x over previous
//
#include <hip/hip_runtime.h>
#include <math.h>

#define N_NODES 100000
#define N_EDGES 1600000
#define F_IN 128
#define H_DIM 128
#define C_OUT 40
#define BN_EPS 1e-5f
#define NSEG (N_EDGES + N_NODES)
#define SCAN_T 512
#define SCAN_NB ((N_NODES + 1 + SCAN_T - 1) / SCAN_T)   // 196

typedef unsigned short u16;
typedef unsigned int u32;
typedef __attribute__((ext_vector_type(8))) __bf16 bf16x8;
typedef __attribute__((ext_vector_type(4))) float f32x4;

__device__ __forceinline__ u16 f2bf(float f) {              // RNE
    u32 u = __float_as_uint(f);
    u += 0x7FFFu + ((u >> 16) & 1u);
    return (u16)(u >> 16);
}
__device__ __forceinline__ float bf2f(u16 h) {
    return __uint_as_float(((u32)h) << 16);
}

// ---------------- CSR build ----------------
__global__ __launch_bounds__(256) void cnt_init(int* cnt) {
    int i = blockIdx.x * 256 + threadIdx.x;
    if (i < N_NODES) cnt[i] = 1;                 // self-loop occupies slot 0
}

__global__ __launch_bounds__(256) void cnt_count(const int* __restrict__ dst,
                                                 int* __restrict__ cnt,
                                                 int* __restrict__ aux) {
    int e = blockIdx.x * 256 + threadIdx.x;
    if (e < N_EDGES) aux[e] = atomicAdd(&cnt[dst[e]], 1);   // returns >= 1
}

__global__ __launch_bounds__(SCAN_T) void scan_block(const int* __restrict__ cnt,
                                                     int* __restrict__ rowoff,
                                                     int* __restrict__ bsum) {
    __shared__ int tmp[SCAN_T];
    int i = blockIdx.x * SCAN_T + threadIdx.x;
    int v = (i < N_NODES) ? cnt[i] : 0;
    tmp[threadIdx.x] = v;
    __syncthreads();
    for (int off = 1; off < SCAN_T; off <<= 1) {
        int t = (threadIdx.x >= off) ? tmp[threadIdx.x - off] : 0;
        __syncthreads();
        tmp[threadIdx.x] += t;
        __syncthreads();
    }
    if (i <= N_NODES) rowoff[i] = tmp[threadIdx.x] - v;   // exclusive
    if (threadIdx.x == SCAN_T - 1) bsum[blockIdx.x] = tmp[SCAN_T - 1];
}

__global__ void scan_bsum(int* bsum) {
    if (threadIdx.x == 0) {
        int acc = 0;
        for (int b = 0; b < SCAN_NB; ++b) { int v = bsum[b]; bsum[b] = acc; acc += v; }
    }
}

__global__ __launch_bounds__(SCAN_T) void scan_add(int* __restrict__ rowoff,
                                                   const int* __restrict__ bsum) {
    int i = blockIdx.x * SCAN_T + threadIdx.x;
    if (i <= N_NODES) rowoff[i] += bsum[blockIdx.x];
}

__global__ __launch_bounds__(256) void dinv_self(const int* __restrict__ cnt,
                                                 const int* __restrict__ rowoff,
                                                 float* __restrict__ dinv,
                                                 int* __restrict__ csr) {
    int i = blockIdx.x * 256 + threadIdx.x;
    if (i < N_NODES) {
        dinv[i] = rsqrtf((float)cnt[i]);
        csr[rowoff[i]] = i;
    }
}

__global__ __launch_bounds__(256) void fill_edges(const int* __restrict__ src,
                                                  const int* __restrict__ dst,
                                                  const int* __restrict__ rowoff,
                                                  const int* __restrict__ aux,
                                                  int* __restrict__ csr) {
    int e = blockIdx.x * 256 + threadIdx.x;
    if (e < N_EDGES) csr[rowoff[dst[e]] + aux[e]] = src[e];
}

// ---------------- x -> bf16 (RNE) ----------------
__global__ __launch_bounds__(256) void xconvert(const float* __restrict__ x,
                                                u16* __restrict__ xb) {
    int i = blockIdx.x * 256 + threadIdx.x;      // exactly 3.2M threads
    float4 v = ((const float4*)x)[i];
    ushort4 o;
    o.x = f2bf(v.x); o.y = f2bf(v.y); o.z = f2bf(v.z); o.w = f2bf(v.w);
    ((ushort4*)xb)[i] = o;
}

// W1 [k][n] f32 -> W1t [n][k] bf16
__global__ __launch_bounds__(256) void wconvert(const float* __restrict__ W1,
                                                u16* __restrict__ W1t) {
    int i = blockIdx.x * 256 + threadIdx.x;      // 16384
    int k = i >> 7, n = i & 127;
    W1t[n * H_DIM + k] = f2bf(W1[k * H_DIM + n]);
}

// ---------------- gather layer 1 over bf16 x -> bf16 agg ----------------
__global__ __launch_bounds__(256) void gather_x(const int* __restrict__ rowoff,
                                                const int* __restrict__ csr,
                                                const float* __restrict__ dinv,
                                                const u16* __restrict__ xb,
                                                u16* __restrict__ aggb) {
    int node = blockIdx.x * 8 + (threadIdx.x >> 5);      // grid exact: N%8==0
    int lane4 = (threadIdx.x & 31) * 4;
    int beg = rowoff[node], end = rowoff[node + 1];
    float dd = dinv[node];
    float4 a0 = {0, 0, 0, 0}, a1 = {0, 0, 0, 0};
    int e = beg;
    for (; e + 1 < end; e += 2) {
        int s0 = csr[e], s1 = csr[e + 1];
        float w0 = dinv[s0] * dd, w1 = dinv[s1] * dd;
        ushort4 v0 = *(const ushort4*)(xb + (size_t)s0 * F_IN + lane4);
        ushort4 v1 = *(const ushort4*)(xb + (size_t)s1 * F_IN + lane4);
        a0.x = fmaf(bf2f(v0.x), w0, a0.x); a0.y = fmaf(bf2f(v0.y), w0, a0.y);
        a0.z = fmaf(bf2f(v0.z), w0, a0.z); a0.w = fmaf(bf2f(v0.w), w0, a0.w);
        a1.x = fmaf(bf2f(v1.x), w1, a1.x); a1.y = fmaf(bf2f(v1.y), w1, a1.y);
        a1.z = fmaf(bf2f(v1.z), w1, a1.z); a1.w = fmaf(bf2f(v1.w), w1, a1.w);
    }
    if (e < end) {
        int s0 = csr[e];
        float w0 = dinv[s0] * dd;
        ushort4 v0 = *(const ushort4*)(xb + (size_t)s0 * F_IN + lane4);
        a0.x = fmaf(bf2f(v0.x), w0, a0.x); a0.y = fmaf(bf2f(v0.y), w0, a0.y);
        a0.z = fmaf(bf2f(v0.z), w0, a0.z); a0.w = fmaf(bf2f(v0.w), w0, a0.w);
    }
    uint2 p;
    p.x = (u32)f2bf(a0.x + a1.x) | ((u32)f2bf(a0.y + a1.y) << 16);
    p.y = (u32)f2bf(a0.z + a1.z) | ((u32)f2bf(a0.w + a1.w) << 16);
    *(uint2*)(aggb + (size_t)node * H_DIM + lane4) = p;
}

// ------------- GEMM1 via MFMA: hb = relu(aggb@W1 + b1) (bf16), + BN stats ---
// 128 nodes/block, 4 waves; wave w owns channels [32w, 32w+32).
// Swapped operands: A_op = W1t frag (ch x k), B_op = node frag (k x node),
// D[ch][node]. Lane: node = l&15, channels 4*(l>>4)+i (+16 per tile).
#define G1_ROWS 128
#define G1_LD 136   // shorts (272 B row): quarter-wave banks 4*((r+g) mod 8) -> 2-way, free
__global__ __launch_bounds__(256) void gemm1_mfma(const u16* __restrict__ aggb,
                                                  const u16* __restrict__ W1t,
                                                  const float* __restrict__ b1,
                                                  u16* __restrict__ hb,
                                                  float* __restrict__ gsums,
                                                  float* __restrict__ gsumsq) {
    __shared__ u16 As[G1_ROWS * G1_LD];   // 34.8 KB
    int tid = threadIdx.x;
    int base = blockIdx.x * G1_ROWS;

    {   // stage 128 node rows (256 B each), clamped at tail
        int row = tid >> 1, half = tid & 1;
        int gr = base + row; if (gr >= N_NODES) gr = N_NODES - 1;
        const int4* gsrc = (const int4*)(aggb + (size_t)gr * H_DIM + half * 64);
        int4* ldst = (int4*)(As + row * G1_LD + half * 64);
        #pragma unroll
        for (int i = 0; i < 8; ++i) ldst[i] = gsrc[i];
    }
    __syncthreads();

    int lane = tid & 63, w = tid >> 6;
    int r = lane & 15, g = lane >> 4;

    bf16x8 wf[2][4];   // [ch-tile][kstep], resident
    #pragma unroll
    for (int t = 0; t < 2; ++t)
        #pragma unroll
        for (int ks = 0; ks < 4; ++ks)
            wf[t][ks] = *(const bf16x8*)(W1t + (w * 32 + t * 16 + r) * H_DIM + ks * 32 + g * 8);

    float bch[2][4];
    #pragma unroll
    for (int t = 0; t < 2; ++t)
        #pragma unroll
        for (int i = 0; i < 4; ++i)
            bch[t][i] = b1[w * 32 + t * 16 + 4 * g + i];

    float cs[8] = {}, cq[8] = {};

    for (int rt = 0; rt < 8; ++rt) {
        f32x4 acc0 = {0.f, 0.f, 0.f, 0.f}, acc1 = {0.f, 0.f, 0.f, 0.f};
        #pragma unroll
        for (int ks = 0; ks < 4; ++ks) {
            bf16x8 nf = *(const bf16x8*)(As + (rt * 16 + r) * G1_LD + ks * 32 + g * 8);
            acc0 = __builtin_amdgcn_mfma_f32_16x16x32_bf16(wf[0][ks], nf, acc0, 0, 0, 0);
            acc1 = __builtin_amdgcn_mfma_f32_16x16x32_bf16(wf[1][ks], nf, acc1, 0, 0, 0);
        }
        int node = base + rt * 16 + r;
        if (node < N_NODES) {
            float o0[4], o1[4];
            #pragma unroll
            for (int i = 0; i < 4; ++i) {
                o0[i] = fmaxf(acc0[i] + bch[0][i], 0.f);
                o1[i] = fmaxf(acc1[i] + bch[1][i], 0.f);
                cs[i]     += o0[i]; cq[i]     += o0[i] * o0[i];
                cs[4 + i] += o1[i]; cq[4 + i] += o1[i] * o1[i];
            }
            uint2 p0, p1;
            p0.x = (u32)f2bf(o0[0]) | ((u32)f2bf(o0[1]) << 16);
            p0.y = (u32)f2bf(o0[2]) | ((u32)f2bf(o0[3]) << 16);
            p1.x = (u32)f2bf(o1[0]) | ((u32)f2bf(o1[1]) << 16);
            p1.y = (u32)f2bf(o1[2]) | ((u32)f2bf(o1[3]) << 16);
            u16* hp = hb + (size_t)node * H_DIM + w * 32 + 4 * g;
            *(uint2*)hp = p0;
            *(uint2*)(hp + 16) = p1;
        }
    }

    // reduce stats over the 16-lane node dimension, then 1 atomic per channel
    #pragma unroll
    for (int j = 0; j < 8; ++j) {
        #pragma unroll
        for (int m = 1; m < 16; m <<= 1) {
            cs[j] += __shfl_xor(cs[j], m, 16);
            cq[j] += __shfl_xor(cq[j], m, 16);
        }
    }
    if (r == 0) {
        #pragma unroll
        for (int j = 0; j < 8; ++j) {
            int c = w * 32 + (j >> 2) * 16 + 4 * g + (j & 3);
            atomicAdd(&gsums[c], cs[j]);
            atomicAdd(&gsumsq[c], cq[j]);
        }
    }
}

__global__ void bn_final(const float* __restrict__ sums,
                         const float* __restrict__ sumsq,
                         const float* __restrict__ gamma,
                         const float* __restrict__ beta,
                         float* __restrict__ scale,
                         float* __restrict__ shift) {
    int c = threadIdx.x;
    if (c < H_DIM) {
        const float invn = 1.0f / (float)N_NODES;
        float mean = sums[c] * invn;
        float var = sumsq[c] * invn - mean * mean;
        float sc = gamma[c] * rsqrtf(var + BN_EPS);
        scale[c] = sc;
        shift[c] = beta[c] - mean * sc;
    }
}

// ---------------- GEMM2: h2b(bf16) = (hb*scale+shift) @ W2  (128->40) ----
#define G2_ROWS 128
#define XS_LD 132
#define W2_LD 132
__global__ __launch_bounds__(256) void gemm2(const u16* __restrict__ hb,
                                             const float* __restrict__ W2,
                                             const float* __restrict__ scale,
                                             const float* __restrict__ shift,
                                             u16* __restrict__ h2b) {
    __shared__ float W2t[C_OUT * W2_LD];
    __shared__ float Xs[G2_ROWS * XS_LD];

    for (int i = threadIdx.x; i < H_DIM * C_OUT; i += 256) {
        int k = i / C_OUT, c = i % C_OUT;
        W2t[c * W2_LD + k] = W2[i];
    }
    int base = blockIdx.x * G2_ROWS;
    for (int i = threadIdx.x; i < G2_ROWS * H_DIM / 8; i += 256) {   // 2048
        int rrow = i >> 4;
        int k8 = (i & 15) * 8;
        int gr = base + rrow;
        if (gr >= N_NODES) gr = N_NODES - 1;
        int4 raw = *(const int4*)(hb + (size_t)gr * H_DIM + k8);
        const u16* hv = (const u16*)&raw;
        float4 sc0 = *(const float4*)(scale + k8), sc1 = *(const float4*)(scale + k8 + 4);
        float4 sh0 = *(const float4*)(shift + k8), sh1 = *(const float4*)(shift + k8 + 4);
        float4 o0 = {fmaf(bf2f(hv[0]), sc0.x, sh0.x), fmaf(bf2f(hv[1]), sc0.y, sh0.y),
                     fmaf(bf2f(hv[2]), sc0.z, sh0.z), fmaf(bf2f(hv[3]), sc0.w, sh0.w)};
        float4 o1 = {fmaf(bf2f(hv[4]), sc1.x, sh1.x), fmaf(bf2f(hv[5]), sc1.y, sh1.y),
                     fmaf(bf2f(hv[6]), sc1.z, sh1.z), fmaf(bf2f(hv[7]), sc1.w, sh1.w)};
        *(float4*)&Xs[rrow * XS_LD + k8] = o0;
        *(float4*)&Xs[rrow * XS_LD + k8 + 4] = o1;
    }
    __syncthreads();

    int colg = threadIdx.x & 3;    // cols colg*10 + j
    int rowg = threadIdx.x >> 2;

    float acc0[10] = {}, acc1[10] = {};
    for (int k = 0; k < H_DIM; k += 4) {
        float4 xa = *(const float4*)&Xs[rowg * XS_LD + k];
        float4 xb = *(const float4*)&Xs[(rowg + 64) * XS_LD + k];
        #pragma unroll
        for (int j = 0; j < 10; ++j) {
            int c = colg * 10 + j;
            float4 wv = *(const float4*)&W2t[c * W2_LD + k];
            acc0[j] = fmaf(xa.x, wv.x, acc0[j]);
            acc0[j] = fmaf(xa.y, wv.y, acc0[j]);
            acc0[j] = fmaf(xa.z, wv.z, acc0[j]);
            acc0[j] = fmaf(xa.w, wv.w, acc0[j]);
            acc1[j] = fmaf(xb.x, wv.x, acc1[j]);
            acc1[j] = fmaf(xb.y, wv.y, acc1[j]);
            acc1[j] = fmaf(xb.z, wv.z, acc1[j]);
            acc1[j] = fmaf(xb.w, wv.w, acc1[j]);
        }
    }
    int gr0 = base + rowg, gr1 = base + rowg + 64;
    if (gr0 < N_NODES) {
        u16* p = h2b + (size_t)gr0 * C_OUT + colg * 10;
        #pragma unroll
        for (int t = 0; t < 5; ++t) {
            u32 v = (u32)f2bf(acc0[2 * t]) | ((u32)f2bf(acc0[2 * t + 1]) << 16);
            *(u32*)(p + 2 * t) = v;
        }
    }
    if (gr1 < N_NODES) {
        u16* p = h2b + (size_t)gr1 * C_OUT + colg * 10;
        #pragma unroll
        for (int t = 0; t < 5; ++t) {
            u32 v = (u32)f2bf(acc1[2 * t]) | ((u32)f2bf(acc1[2 * t + 1]) << 16);
            *(u32*)(p + 2 * t) = v;
        }
    }
}

// ------- gather layer 2 (bf16) + b2 + log_softmax fused, 16 lanes/node -------
__global__ __launch_bounds__(256) void gather2_fused(const int* __restrict__ rowoff,
                                                     const int* __restrict__ csr,
                                                     const float* __restrict__ dinv,
                                                     const u16* __restrict__ h2b,
                                                     const float* __restrict__ b2,
                                                     float* __restrict__ out) {
    int node = blockIdx.x * 16 + (threadIdx.x >> 4);     // grid exact: N%16==0
    int q = threadIdx.x & 15;
    int beg = rowoff[node], end = rowoff[node + 1];
    float dd = dinv[node];
    float4 a0 = {0, 0, 0, 0}, a1 = {0, 0, 0, 0};
    int e = beg;
    for (; e + 1 < end; e += 2) {
        int s0 = csr[e], s1 = csr[e + 1];
        float w0 = dinv[s0] * dd, w1 = dinv[s1] * dd;
        if (q < 10) {
            ushort4 v0 = *(const ushort4*)(h2b + (size_t)s0 * C_OUT + q * 4);
            ushort4 v1 = *(const ushort4*)(h2b + (size_t)s1 * C_OUT + q * 4);
            a0.x = fmaf(bf2f(v0.x), w0, a0.x); a0.y = fmaf(bf2f(v0.y), w0, a0.y);
            a0.z = fmaf(bf2f(v0.z), w0, a0.z); a0.w = fmaf(bf2f(v0.w), w0, a0.w);
            a1.x = fmaf(bf2f(v1.x), w1, a1.x); a1.y = fmaf(bf2f(v1.y), w1, a1.y);
            a1.z = fmaf(bf2f(v1.z), w1, a1.z); a1.w = fmaf(bf2f(v1.w), w1, a1.w);
        }
    }
    if (e < end) {
        int s0 = csr[e];
        float w0 = dinv[s0] * dd;
        if (q < 10) {
            ushort4 v0 = *(const ushort4*)(h2b + (size_t)s0 * C_OUT + q * 4);
            a0.x = fmaf(bf2f(v0.x), w0, a0.x); a0.y = fmaf(bf2f(v0.y), w0, a0.y);
            a0.z = fmaf(bf2f(v0.z), w0, a0.z); a0.w = fmaf(bf2f(v0.w), w0, a0.w);
        }
    }
    float4 r = {a0.x + a1.x, a0.y + a1.y, a0.z + a1.z, a0.w + a1.w};
    float m = -INFINITY;
    if (q < 10) {
        float4 bv = *(const float4*)(b2 + q * 4);
        r.x += bv.x; r.y += bv.y; r.z += bv.z; r.w += bv.w;
        m = fmaxf(fmaxf(r.x, r.y), fmaxf(r.z, r.w));
    }
    #pragma unroll
    for (int off = 1; off < 16; off <<= 1) m = fmaxf(m, __shfl_xor(m, off, 16));
    float ex = 0.f;
    if (q < 10)
        ex = expf(r.x - m) + expf(r.y - m) + expf(r.z - m) + expf(r.w - m);
    #pragma unroll
    for (int off = 1; off < 16; off <<= 1) ex += __shfl_xor(ex, off, 16);
    float lse = logf(ex) + m;
    if (q < 10) {
        float4 o = {r.x - lse, r.y - lse, r.z - lse, r.w - lse};
        *(float4*)(out + (size_t)node * C_OUT + q * 4) = o;
    }
}

// ---------------- launch ----------------
extern "C" void kernel_launch(void* const* d_in, const int* in_sizes, int n_in,
                              void* d_out, int out_size, void* d_ws, size_t ws_size,
                              hipStream_t stream) {
    const float* x     = (const float*)d_in[0];
    const int*   eidx  = (const int*)d_in[1];
    const float* W1    = (const float*)d_in[2];
    const float* b1    = (const float*)d_in[3];
    const float* gamma = (const float*)d_in[4];
    const float* beta  = (const float*)d_in[5];
    const float* W2    = (const float*)d_in[6];
    const float* b2    = (const float*)d_in[7];
    float* out = (float*)d_out;

    const int* src = eidx;
    const int* dst = eidx + N_EDGES;

    // workspace layout (4B units)
    float* ws = (float*)d_ws;
    int*   cnt    = (int*)ws;                  // N
    float* dinv   = ws + 100000;               // N
    int*   rowoff = (int*)(ws + 200000);       // N+1
    int*   bsum   = (int*)(ws + 300032);       // SCAN_NB
    int*   aux    = (int*)(ws + 301056);       // E
    int*   csr    = (int*)(ws + 1901056);      // NSEG
    u16*   xb     = (u16*)(ws + 3601056);      // N*128 bf16; hb aliases (xb dead after gather_x)
    u16*   hb     = (u16*)(ws + 3601056);
    u16*   aggb   = (u16*)(ws + 10001056);     // N*128 bf16
    u16*   W1t    = (u16*)(ws + 16401056);     // 128*128 bf16
    u16*   h2b    = (u16*)(ws + 16409248);     // N*40 bf16
    float* stats  = ws + 18409248;             // 512
    float* sums = stats, *sumsq = stats + 128, *scale = stats + 256, *shift = stats + 384;

    size_t needed = (size_t)(18409248 + 512) * 4;
    if (ws_size < needed) return;

    hipMemsetAsync(stats, 0, 512 * 4, stream);

    // CSR build (atomic-free fill)
    cnt_init<<<(N_NODES + 255) / 256, 256, 0, stream>>>(cnt);
    cnt_count<<<(N_EDGES + 255) / 256, 256, 0, stream>>>(dst, cnt, aux);
    scan_block<<<SCAN_NB, SCAN_T, 0, stream>>>(cnt, rowoff, bsum);
    scan_bsum<<<1, 64, 0, stream>>>(bsum);
    scan_add<<<SCAN_NB, SCAN_T, 0, stream>>>(rowoff, bsum);
    dinv_self<<<(N_NODES + 255) / 256, 256, 0, stream>>>(cnt, rowoff, dinv, csr);
    fill_edges<<<(N_EDGES + 255) / 256, 256, 0, stream>>>(src, dst, rowoff, aux, csr);

    // layer 1
    xconvert<<<N_NODES * F_IN / 4 / 256, 256, 0, stream>>>(x, xb);
    wconvert<<<F_IN * H_DIM / 256, 256, 0, stream>>>(W1, W1t);
    gather_x<<<N_NODES / 8, 256, 0, stream>>>(rowoff, csr, dinv, xb, aggb);
    gemm1_mfma<<<(N_NODES + G1_ROWS - 1) / G1_ROWS, 256, 0, stream>>>(aggb, W1t, b1, hb, sums, sumsq);
    bn_final<<<1, 128, 0, stream>>>(sums, sumsq, gamma, beta, scale, shift);

    // layer 2
    gemm2<<<(N_NODES + G2_ROWS - 1) / G2_ROWS, 256, 0, stream>>>(hb, W2, scale, shift, h2b);
    gather2_fused<<<N_NODES / 16, 256, 0, stream>>>(rowoff, csr, dinv, h2b, b2, out);
}

// Round 5
// 294.242 us; speedup vs baseline: 11.5048x; 1.3373x over previous
//
#include <hip/hip_runtime.h>
#include <math.h>

#define N_NODES 100000
#define N_EDGES 1600000
#define F_IN 128
#define H_DIM 128
#define C_OUT 40
#define BN_EPS 1e-5f
#define NSEG (N_EDGES + N_NODES)
#define SCAN_T 512
#define SCAN_NB ((N_NODES + 1 + SCAN_T - 1) / SCAN_T)   // 196

#define G1_ROWS 128
#define G1_LD 136          // shorts: 272 B row; wave64 b128 reads hit the 8-cycle LDS floor
#define G1_NB ((N_NODES + G1_ROWS - 1) / G1_ROWS)       // 782
#define PS_LD 800          // pstats stride (>= G1_NB)

typedef unsigned short u16;
typedef unsigned int u32;
typedef __attribute__((ext_vector_type(8))) __bf16 bf16x8;
typedef __attribute__((ext_vector_type(4))) float f32x4;

__device__ __forceinline__ u16 f2bf(float f) {              // RNE
    u32 u = __float_as_uint(f);
    u += 0x7FFFu + ((u >> 16) & 1u);
    return (u16)(u >> 16);
}
__device__ __forceinline__ float bf2f(u16 h) {
    return __uint_as_float(((u32)h) << 16);
}

// ---------------- CSR build ----------------
__global__ __launch_bounds__(256) void cnt_init(int* cnt) {
    int i = blockIdx.x * 256 + threadIdx.x;
    if (i < N_NODES) cnt[i] = 1;                 // self-loop occupies slot 0
}

__global__ __launch_bounds__(256) void cnt_count(const int* __restrict__ dst,
                                                 int* __restrict__ cnt,
                                                 int* __restrict__ aux) {
    int e = blockIdx.x * 256 + threadIdx.x;
    if (e < N_EDGES) aux[e] = atomicAdd(&cnt[dst[e]], 1);   // returns >= 1
}

__global__ __launch_bounds__(SCAN_T) void scan_block(const int* __restrict__ cnt,
                                                     int* __restrict__ rowoff,
                                                     int* __restrict__ bsum) {
    __shared__ int tmp[SCAN_T];
    int i = blockIdx.x * SCAN_T + threadIdx.x;
    int v = (i < N_NODES) ? cnt[i] : 0;
    tmp[threadIdx.x] = v;
    __syncthreads();
    for (int off = 1; off < SCAN_T; off <<= 1) {
        int t = (threadIdx.x >= off) ? tmp[threadIdx.x - off] : 0;
        __syncthreads();
        tmp[threadIdx.x] += t;
        __syncthreads();
    }
    if (i <= N_NODES) rowoff[i] = tmp[threadIdx.x] - v;   // exclusive
    if (threadIdx.x == SCAN_T - 1) bsum[blockIdx.x] = tmp[SCAN_T - 1];
}

__global__ void scan_bsum(int* bsum) {
    if (threadIdx.x == 0) {
        int acc = 0;
        for (int b = 0; b < SCAN_NB; ++b) { int v = bsum[b]; bsum[b] = acc; acc += v; }
    }
}

__global__ __launch_bounds__(SCAN_T) void scan_add(int* __restrict__ rowoff,
                                                   const int* __restrict__ bsum) {
    int i = blockIdx.x * SCAN_T + threadIdx.x;
    if (i <= N_NODES) rowoff[i] += bsum[blockIdx.x];
}

__global__ __launch_bounds__(256) void dinv_self(const int* __restrict__ cnt,
                                                 const int* __restrict__ rowoff,
                                                 float* __restrict__ dinv,
                                                 int* __restrict__ csr) {
    int i = blockIdx.x * 256 + threadIdx.x;
    if (i < N_NODES) {
        dinv[i] = rsqrtf((float)cnt[i]);
        csr[rowoff[i]] = i;
    }
}

__global__ __launch_bounds__(256) void fill_edges(const int* __restrict__ src,
                                                  const int* __restrict__ dst,
                                                  const int* __restrict__ rowoff,
                                                  const int* __restrict__ aux,
                                                  int* __restrict__ csr) {
    int e = blockIdx.x * 256 + threadIdx.x;
    if (e < N_EDGES) csr[rowoff[dst[e]] + aux[e]] = src[e];
}

// ---------------- x -> bf16 (RNE) ----------------
__global__ __launch_bounds__(256) void xconvert(const float* __restrict__ x,
                                                u16* __restrict__ xb) {
    int i = blockIdx.x * 256 + threadIdx.x;      // exactly 3.2M threads
    float4 v = ((const float4*)x)[i];
    ushort4 o;
    o.x = f2bf(v.x); o.y = f2bf(v.y); o.z = f2bf(v.z); o.w = f2bf(v.w);
    ((ushort4*)xb)[i] = o;
}

// W1 [k][n] f32 -> W1t [n][k] bf16
__global__ __launch_bounds__(256) void wconvert(const float* __restrict__ W1,
                                                u16* __restrict__ W1t) {
    int i = blockIdx.x * 256 + threadIdx.x;      // 16384
    int k = i >> 7, n = i & 127;
    W1t[n * H_DIM + k] = f2bf(W1[k * H_DIM + n]);
}

// ---------------- gather layer 1 over bf16 x -> bf16 agg ----------------
__global__ __launch_bounds__(256) void gather_x(const int* __restrict__ rowoff,
                                                const int* __restrict__ csr,
                                                const float* __restrict__ dinv,
                                                const u16* __restrict__ xb,
                                                u16* __restrict__ aggb) {
    int node = blockIdx.x * 8 + (threadIdx.x >> 5);      // grid exact: N%8==0
    int lane4 = (threadIdx.x & 31) * 4;
    int beg = rowoff[node], end = rowoff[node + 1];
    float dd = dinv[node];
    float4 a0 = {0, 0, 0, 0}, a1 = {0, 0, 0, 0};
    int e = beg;
    for (; e + 1 < end; e += 2) {
        int s0 = csr[e], s1 = csr[e + 1];
        float w0 = dinv[s0] * dd, w1 = dinv[s1] * dd;
        ushort4 v0 = *(const ushort4*)(xb + (size_t)s0 * F_IN + lane4);
        ushort4 v1 = *(const ushort4*)(xb + (size_t)s1 * F_IN + lane4);
        a0.x = fmaf(bf2f(v0.x), w0, a0.x); a0.y = fmaf(bf2f(v0.y), w0, a0.y);
        a0.z = fmaf(bf2f(v0.z), w0, a0.z); a0.w = fmaf(bf2f(v0.w), w0, a0.w);
        a1.x = fmaf(bf2f(v1.x), w1, a1.x); a1.y = fmaf(bf2f(v1.y), w1, a1.y);
        a1.z = fmaf(bf2f(v1.z), w1, a1.z); a1.w = fmaf(bf2f(v1.w), w1, a1.w);
    }
    if (e < end) {
        int s0 = csr[e];
        float w0 = dinv[s0] * dd;
        ushort4 v0 = *(const ushort4*)(xb + (size_t)s0 * F_IN + lane4);
        a0.x = fmaf(bf2f(v0.x), w0, a0.x); a0.y = fmaf(bf2f(v0.y), w0, a0.y);
        a0.z = fmaf(bf2f(v0.z), w0, a0.z); a0.w = fmaf(bf2f(v0.w), w0, a0.w);
    }
    uint2 p;
    p.x = (u32)f2bf(a0.x + a1.x) | ((u32)f2bf(a0.y + a1.y) << 16);
    p.y = (u32)f2bf(a0.z + a1.z) | ((u32)f2bf(a0.w + a1.w) << 16);
    *(uint2*)(aggb + (size_t)node * H_DIM + lane4) = p;
}

// ------------- GEMM1 via MFMA: hb = relu(aggb@W1 + b1) (bf16) --------------
// BN partial stats go to pstats[c][blk] with PLAIN stores (no atomics!).
// 128 nodes/block, 4 waves; wave w owns channels [32w, 32w+32).
// Swapped operands: A_op = W1t frag (ch x k), B_op = node frag (k x node),
// D[ch][node]. Lane: node = l&15, channels 4*(l>>4)+i (+16 per tile).
__global__ __launch_bounds__(256) void gemm1_mfma(const u16* __restrict__ aggb,
                                                  const u16* __restrict__ W1t,
                                                  const float* __restrict__ b1,
                                                  u16* __restrict__ hb,
                                                  float* __restrict__ pstats) {
    __shared__ u16 As[G1_ROWS * G1_LD];   // 34.8 KB
    int tid = threadIdx.x;
    int base = blockIdx.x * G1_ROWS;

    {   // stage 128 node rows (256 B each), clamped at tail
        int row = tid >> 1, half = tid & 1;
        int gr = base + row; if (gr >= N_NODES) gr = N_NODES - 1;
        const int4* gsrc = (const int4*)(aggb + (size_t)gr * H_DIM + half * 64);
        int4* ldst = (int4*)(As + row * G1_LD + half * 64);
        #pragma unroll
        for (int i = 0; i < 8; ++i) ldst[i] = gsrc[i];
    }
    __syncthreads();

    int lane = tid & 63, w = tid >> 6;
    int r = lane & 15, g = lane >> 4;

    bf16x8 wf[2][4];   // [ch-tile][kstep], resident
    #pragma unroll
    for (int t = 0; t < 2; ++t)
        #pragma unroll
        for (int ks = 0; ks < 4; ++ks)
            wf[t][ks] = *(const bf16x8*)(W1t + (w * 32 + t * 16 + r) * H_DIM + ks * 32 + g * 8);

    float bch[2][4];
    #pragma unroll
    for (int t = 0; t < 2; ++t)
        #pragma unroll
        for (int i = 0; i < 4; ++i)
            bch[t][i] = b1[w * 32 + t * 16 + 4 * g + i];

    float cs[8] = {}, cq[8] = {};

    for (int rt = 0; rt < 8; ++rt) {
        f32x4 acc0 = {0.f, 0.f, 0.f, 0.f}, acc1 = {0.f, 0.f, 0.f, 0.f};
        #pragma unroll
        for (int ks = 0; ks < 4; ++ks) {
            bf16x8 nf = *(const bf16x8*)(As + (rt * 16 + r) * G1_LD + ks * 32 + g * 8);
            acc0 = __builtin_amdgcn_mfma_f32_16x16x32_bf16(wf[0][ks], nf, acc0, 0, 0, 0);
            acc1 = __builtin_amdgcn_mfma_f32_16x16x32_bf16(wf[1][ks], nf, acc1, 0, 0, 0);
        }
        int node = base + rt * 16 + r;
        if (node < N_NODES) {
            float o0[4], o1[4];
            #pragma unroll
            for (int i = 0; i < 4; ++i) {
                o0[i] = fmaxf(acc0[i] + bch[0][i], 0.f);
                o1[i] = fmaxf(acc1[i] + bch[1][i], 0.f);
                cs[i]     += o0[i]; cq[i]     += o0[i] * o0[i];
                cs[4 + i] += o1[i]; cq[4 + i] += o1[i] * o1[i];
            }
            uint2 p0, p1;
            p0.x = (u32)f2bf(o0[0]) | ((u32)f2bf(o0[1]) << 16);
            p0.y = (u32)f2bf(o0[2]) | ((u32)f2bf(o0[3]) << 16);
            p1.x = (u32)f2bf(o1[0]) | ((u32)f2bf(o1[1]) << 16);
            p1.y = (u32)f2bf(o1[2]) | ((u32)f2bf(o1[3]) << 16);
            u16* hp = hb + (size_t)node * H_DIM + w * 32 + 4 * g;
            *(uint2*)hp = p0;
            *(uint2*)(hp + 16) = p1;
        }
    }

    // reduce stats over the 16-lane node dimension, then plain stores
    #pragma unroll
    for (int j = 0; j < 8; ++j) {
        #pragma unroll
        for (int m = 1; m < 16; m <<= 1) {
            cs[j] += __shfl_xor(cs[j], m, 16);
            cq[j] += __shfl_xor(cq[j], m, 16);
        }
    }
    if (r == 0) {
        #pragma unroll
        for (int j = 0; j < 8; ++j) {
            int c = w * 32 + (j >> 2) * 16 + 4 * g + (j & 3);
            pstats[c * PS_LD + blockIdx.x] = cs[j];
            pstats[(128 + c) * PS_LD + blockIdx.x] = cq[j];
        }
    }
}

// ---- reduce per-block partials -> scale/shift (one block per channel) ----
__global__ __launch_bounds__(256) void stats_final(const float* __restrict__ pstats,
                                                   const float* __restrict__ gamma,
                                                   const float* __restrict__ beta,
                                                   float* __restrict__ scale,
                                                   float* __restrict__ shift) {
    __shared__ float ls[256], lq[256];
    int c = blockIdx.x, t = threadIdx.x;
    float s = 0.f, q = 0.f;
    for (int b = t; b < G1_NB; b += 256) {
        s += pstats[c * PS_LD + b];
        q += pstats[(128 + c) * PS_LD + b];
    }
    ls[t] = s; lq[t] = q;
    __syncthreads();
    for (int off = 128; off; off >>= 1) {
        if (t < off) { ls[t] += ls[t + off]; lq[t] += lq[t + off]; }
        __syncthreads();
    }
    if (t == 0) {
        const float invn = 1.0f / (float)N_NODES;
        float mean = ls[0] * invn;
        float var = lq[0] * invn - mean * mean;
        float sc = gamma[c] * rsqrtf(var + BN_EPS);
        scale[c] = sc;
        shift[c] = beta[c] - mean * sc;
    }
}

// ---- fold BN into layer-2 weights: W2t[c][k] = bf16(scale[k]*W2[k][c]),
// padded to 48 channels; K[c] = sum_k shift[k]*W2[k][c] (f32) ----
__global__ __launch_bounds__(256) void w2fold(const float* __restrict__ W2,
                                              const float* __restrict__ scale,
                                              const float* __restrict__ shift,
                                              u16* __restrict__ W2t,
                                              float* __restrict__ K) {
    int t = threadIdx.x;
    for (int i = t; i < 48 * 128; i += 256) {
        int c = i >> 7, k = i & 127;
        W2t[i] = (c < C_OUT) ? f2bf(scale[k] * W2[k * C_OUT + c]) : (u16)0;
    }
    if (t < C_OUT) {
        float a = 0.f;
        for (int k = 0; k < H_DIM; ++k) a += shift[k] * W2[k * C_OUT + t];
        K[t] = a;
    }
}

// ------------- GEMM2 via MFMA: h2b = hb @ W2t  (128 -> 40, bf16) -----------
// Same geometry as gemm1; wave w owns row-tiles {2w, 2w+1}; 3 ch-tiles
// (last half-masked since 40 = 2*16 + 8).
__global__ __launch_bounds__(256) void gemm2_mfma(const u16* __restrict__ hb,
                                                  const u16* __restrict__ W2t,
                                                  u16* __restrict__ h2b) {
    __shared__ u16 As[G1_ROWS * G1_LD];
    int tid = threadIdx.x;
    int base = blockIdx.x * G1_ROWS;

    {
        int row = tid >> 1, half = tid & 1;
        int gr = base + row; if (gr >= N_NODES) gr = N_NODES - 1;
        const int4* gsrc = (const int4*)(hb + (size_t)gr * H_DIM + half * 64);
        int4* ldst = (int4*)(As + row * G1_LD + half * 64);
        #pragma unroll
        for (int i = 0; i < 8; ++i) ldst[i] = gsrc[i];
    }
    __syncthreads();

    int lane = tid & 63, w = tid >> 6;
    int r = lane & 15, g = lane >> 4;

    bf16x8 wf[3][4];
    #pragma unroll
    for (int t = 0; t < 3; ++t)
        #pragma unroll
        for (int ks = 0; ks < 4; ++ks)
            wf[t][ks] = *(const bf16x8*)(W2t + (t * 16 + r) * H_DIM + ks * 32 + g * 8);

    f32x4 acc[2][3];
    #pragma unroll
    for (int i2 = 0; i2 < 2; ++i2)
        #pragma unroll
        for (int t = 0; t < 3; ++t)
            acc[i2][t] = (f32x4){0.f, 0.f, 0.f, 0.f};

    #pragma unroll
    for (int i2 = 0; i2 < 2; ++i2) {
        int rt = 2 * w + i2;
        #pragma unroll
        for (int ks = 0; ks < 4; ++ks) {
            bf16x8 nf = *(const bf16x8*)(As + (rt * 16 + r) * G1_LD + ks * 32 + g * 8);
            acc[i2][0] = __builtin_amdgcn_mfma_f32_16x16x32_bf16(wf[0][ks], nf, acc[i2][0], 0, 0, 0);
            acc[i2][1] = __builtin_amdgcn_mfma_f32_16x16x32_bf16(wf[1][ks], nf, acc[i2][1], 0, 0, 0);
            acc[i2][2] = __builtin_amdgcn_mfma_f32_16x16x32_bf16(wf[2][ks], nf, acc[i2][2], 0, 0, 0);
        }
    }

    #pragma unroll
    for (int i2 = 0; i2 < 2; ++i2) {
        int node = base + (2 * w + i2) * 16 + r;
        if (node < N_NODES) {
            u16* hp = h2b + (size_t)node * C_OUT + 4 * g;
            #pragma unroll
            for (int t = 0; t < 2; ++t) {
                uint2 p;
                p.x = (u32)f2bf(acc[i2][t][0]) | ((u32)f2bf(acc[i2][t][1]) << 16);
                p.y = (u32)f2bf(acc[i2][t][2]) | ((u32)f2bf(acc[i2][t][3]) << 16);
                *(uint2*)(hp + t * 16) = p;
            }
            if (g < 2) {
                uint2 p;
                p.x = (u32)f2bf(acc[i2][2][0]) | ((u32)f2bf(acc[i2][2][1]) << 16);
                p.y = (u32)f2bf(acc[i2][2][2]) | ((u32)f2bf(acc[i2][2][3]) << 16);
                *(uint2*)(hp + 32) = p;
            }
        }
    }
}

// ------- gather layer 2 (bf16) + K*wsum + b2 + log_softmax, 16 lanes/node ---
__global__ __launch_bounds__(256) void gather2_fused(const int* __restrict__ rowoff,
                                                     const int* __restrict__ csr,
                                                     const float* __restrict__ dinv,
                                                     const u16* __restrict__ h2b,
                                                     const float* __restrict__ K,
                                                     const float* __restrict__ b2,
                                                     float* __restrict__ out) {
    int node = blockIdx.x * 16 + (threadIdx.x >> 4);     // grid exact: N%16==0
    int q = threadIdx.x & 15;
    int beg = rowoff[node], end = rowoff[node + 1];
    float dd = dinv[node];
    float4 a0 = {0, 0, 0, 0}, a1 = {0, 0, 0, 0};
    float wsum = 0.f;
    int e = beg;
    for (; e + 1 < end; e += 2) {
        int s0 = csr[e], s1 = csr[e + 1];
        float w0 = dinv[s0] * dd, w1 = dinv[s1] * dd;
        wsum += w0 + w1;
        if (q < 10) {
            ushort4 v0 = *(const ushort4*)(h2b + (size_t)s0 * C_OUT + q * 4);
            ushort4 v1 = *(const ushort4*)(h2b + (size_t)s1 * C_OUT + q * 4);
            a0.x = fmaf(bf2f(v0.x), w0, a0.x); a0.y = fmaf(bf2f(v0.y), w0, a0.y);
            a0.z = fmaf(bf2f(v0.z), w0, a0.z); a0.w = fmaf(bf2f(v0.w), w0, a0.w);
            a1.x = fmaf(bf2f(v1.x), w1, a1.x); a1.y = fmaf(bf2f(v1.y), w1, a1.y);
            a1.z = fmaf(bf2f(v1.z), w1, a1.z); a1.w = fmaf(bf2f(v1.w), w1, a1.w);
        }
    }
    if (e < end) {
        int s0 = csr[e];
        float w0 = dinv[s0] * dd;
        wsum += w0;
        if (q < 10) {
            ushort4 v0 = *(const ushort4*)(h2b + (size_t)s0 * C_OUT + q * 4);
            a0.x = fmaf(bf2f(v0.x), w0, a0.x); a0.y = fmaf(bf2f(v0.y), w0, a0.y);
            a0.z = fmaf(bf2f(v0.z), w0, a0.z); a0.w = fmaf(bf2f(v0.w), w0, a0.w);
        }
    }
    float4 r = {a0.x + a1.x, a0.y + a1.y, a0.z + a1.z, a0.w + a1.w};
    float m = -INFINITY;
    if (q < 10) {
        float4 kv = *(const float4*)(K + q * 4);
        float4 bv = *(const float4*)(b2 + q * 4);
        r.x = fmaf(kv.x, wsum, r.x) + bv.x;
        r.y = fmaf(kv.y, wsum, r.y) + bv.y;
        r.z = fmaf(kv.z, wsum, r.z) + bv.z;
        r.w = fmaf(kv.w, wsum, r.w) + bv.w;
        m = fmaxf(fmaxf(r.x, r.y), fmaxf(r.z, r.w));
    }
    #pragma unroll
    for (int off = 1; off < 16; off <<= 1) m = fmaxf(m, __shfl_xor(m, off, 16));
    float ex = 0.f;
    if (q < 10)
        ex = expf(r.x - m) + expf(r.y - m) + expf(r.z - m) + expf(r.w - m);
    #pragma unroll
    for (int off = 1; off < 16; off <<= 1) ex += __shfl_xor(ex, off, 16);
    float lse = logf(ex) + m;
    if (q < 10) {
        float4 o = {r.x - lse, r.y - lse, r.z - lse, r.w - lse};
        *(float4*)(out + (size_t)node * C_OUT + q * 4) = o;
    }
}

// ---------------- launch ----------------
extern "C" void kernel_launch(void* const* d_in, const int* in_sizes, int n_in,
                              void* d_out, int out_size, void* d_ws, size_t ws_size,
                              hipStream_t stream) {
    const float* x     = (const float*)d_in[0];
    const int*   eidx  = (const int*)d_in[1];
    const float* W1    = (const float*)d_in[2];
    const float* b1    = (const float*)d_in[3];
    const float* gamma = (const float*)d_in[4];
    const float* beta  = (const float*)d_in[5];
    const float* W2    = (const float*)d_in[6];
    const float* b2    = (const float*)d_in[7];
    float* out = (float*)d_out;

    const int* src = eidx;
    const int* dst = eidx + N_EDGES;

    // workspace layout (4B units)
    float* ws = (float*)d_ws;
    int*   cnt    = (int*)ws;                  // N
    float* dinv   = ws + 100000;               // N
    int*   rowoff = (int*)(ws + 200000);       // N+1
    int*   bsum   = (int*)(ws + 300032);       // SCAN_NB
    int*   aux    = (int*)(ws + 301056);       // E
    int*   csr    = (int*)(ws + 1901056);      // NSEG
    u16*   xb     = (u16*)(ws + 3601056);      // N*128 bf16; hb aliases (xb dead after gather_x)
    u16*   hb     = (u16*)(ws + 3601056);
    u16*   aggb   = (u16*)(ws + 10001056);     // N*128 bf16
    u16*   W1t    = (u16*)(ws + 16401056);     // 128*128 bf16
    u16*   h2b    = (u16*)(ws + 16409248);     // N*40 bf16
    float* pstats = ws + 18409248;             // 256*800 f32
    float* scale  = ws + 18614048;             // 128
    float* shift  = ws + 18614176;             // 128
    float* K      = ws + 18614304;             // 64
    u16*   W2t    = (u16*)(ws + 18614368);     // 48*128 bf16

    size_t needed = (size_t)(18614368 + 1536) * 4;
    if (ws_size < needed) return;

    // CSR build (atomic-free fill)
    cnt_init<<<(N_NODES + 255) / 256, 256, 0, stream>>>(cnt);
    cnt_count<<<(N_EDGES + 255) / 256, 256, 0, stream>>>(dst, cnt, aux);
    scan_block<<<SCAN_NB, SCAN_T, 0, stream>>>(cnt, rowoff, bsum);
    scan_bsum<<<1, 64, 0, stream>>>(bsum);
    scan_add<<<SCAN_NB, SCAN_T, 0, stream>>>(rowoff, bsum);
    dinv_self<<<(N_NODES + 255) / 256, 256, 0, stream>>>(cnt, rowoff, dinv, csr);
    fill_edges<<<(N_EDGES + 255) / 256, 256, 0, stream>>>(src, dst, rowoff, aux, csr);

    // layer 1
    xconvert<<<N_NODES * F_IN / 4 / 256, 256, 0, stream>>>(x, xb);
    wconvert<<<F_IN * H_DIM / 256, 256, 0, stream>>>(W1, W1t);
    gather_x<<<N_NODES / 8, 256, 0, stream>>>(rowoff, csr, dinv, xb, aggb);
    gemm1_mfma<<<G1_NB, 256, 0, stream>>>(aggb, W1t, b1, hb, pstats);
    stats_final<<<128, 256, 0, stream>>>(pstats, gamma, beta, scale, shift);
    w2fold<<<1, 256, 0, stream>>>(W2, scale, shift, W2t, K);

    // layer 2
    gemm2_mfma<<<G1_NB, 256, 0, stream>>>(hb, W2t, h2b);
    gather2_fused<<<N_NODES / 16, 256, 0, stream>>>(rowoff, csr, dinv, h2b, K, b2, out);
}

// Round 6
// 266.708 us; speedup vs baseline: 12.6925x; 1.1032x over previous
//
#include <hip/hip_runtime.h>
#include <math.h>

#define N_NODES 100000
#define N_EDGES 1600000
#define F_IN 128
#define H_DIM 128
#define C_OUT 40
#define BN_EPS 1e-5f
#define NSEG (N_EDGES + N_NODES)
#define SCAN_T 512
#define SCAN_NB ((N_NODES + 1 + SCAN_T - 1) / SCAN_T)   // 196

#define G1_ROWS 128
#define G1_LD 136          // shorts: 272 B row
#define G1_NB ((N_NODES + G1_ROWS - 1) / G1_ROWS)       // 782
#define PS_LD 800          // pstats stride (>= G1_NB)

typedef unsigned short u16;
typedef unsigned int u32;
typedef __attribute__((ext_vector_type(8))) __bf16 bf16x8;
typedef __attribute__((ext_vector_type(4))) float f32x4;

__device__ __forceinline__ u16 f2bf(float f) {              // RNE
    u32 u = __float_as_uint(f);
    u += 0x7FFFu + ((u >> 16) & 1u);
    return (u16)(u >> 16);
}
__device__ __forceinline__ float bf2f(u16 h) {
    return __uint_as_float(((u32)h) << 16);
}
// packed dword of 2 bf16 -> two f32 adds (2 VALU each)
__device__ __forceinline__ void add2(float* a0, float* a1, u32 d) {
    *a0 += __uint_as_float(d << 16);
    *a1 += __uint_as_float(d & 0xFFFF0000u);
}

// ---------------- CSR build ----------------
__global__ __launch_bounds__(256) void cnt_init(int* cnt) {
    int i = blockIdx.x * 256 + threadIdx.x;
    if (i < N_NODES) cnt[i] = 1;                 // self-loop occupies slot 0
}

__global__ __launch_bounds__(256) void cnt_count(const int* __restrict__ dst,
                                                 int* __restrict__ cnt,
                                                 int* __restrict__ aux) {
    int e = blockIdx.x * 256 + threadIdx.x;
    if (e < N_EDGES) aux[e] = atomicAdd(&cnt[dst[e]], 1);   // returns >= 1
}

__global__ __launch_bounds__(SCAN_T) void scan_block(const int* __restrict__ cnt,
                                                     int* __restrict__ rowoff,
                                                     int* __restrict__ bsum) {
    __shared__ int tmp[SCAN_T];
    int i = blockIdx.x * SCAN_T + threadIdx.x;
    int v = (i < N_NODES) ? cnt[i] : 0;
    tmp[threadIdx.x] = v;
    __syncthreads();
    for (int off = 1; off < SCAN_T; off <<= 1) {
        int t = (threadIdx.x >= off) ? tmp[threadIdx.x - off] : 0;
        __syncthreads();
        tmp[threadIdx.x] += t;
        __syncthreads();
    }
    if (i <= N_NODES) rowoff[i] = tmp[threadIdx.x] - v;   // exclusive
    if (threadIdx.x == SCAN_T - 1) bsum[blockIdx.x] = tmp[SCAN_T - 1];
}

// parallel exclusive scan of the 196 block sums (one block)
__global__ __launch_bounds__(256) void scan_bsum(int* bsum) {
    __shared__ int tmp[256];
    int t = threadIdx.x;
    int v = (t < SCAN_NB) ? bsum[t] : 0;
    tmp[t] = v;
    __syncthreads();
    for (int off = 1; off < 256; off <<= 1) {
        int u = (t >= off) ? tmp[t - off] : 0;
        __syncthreads();
        tmp[t] += u;
        __syncthreads();
    }
    if (t < SCAN_NB) bsum[t] = tmp[t] - v;   // exclusive
}

__global__ __launch_bounds__(SCAN_T) void scan_add(int* __restrict__ rowoff,
                                                   const int* __restrict__ bsum) {
    int i = blockIdx.x * SCAN_T + threadIdx.x;
    if (i <= N_NODES) rowoff[i] += bsum[blockIdx.x];
}

__global__ __launch_bounds__(256) void dinv_self(const int* __restrict__ cnt,
                                                 const int* __restrict__ rowoff,
                                                 float* __restrict__ dinv,
                                                 int* __restrict__ csr) {
    int i = blockIdx.x * 256 + threadIdx.x;
    if (i < N_NODES) {
        dinv[i] = rsqrtf((float)cnt[i]);
        csr[rowoff[i]] = i;
    }
}

__global__ __launch_bounds__(256) void fill_edges(const int* __restrict__ src,
                                                  const int* __restrict__ dst,
                                                  const int* __restrict__ rowoff,
                                                  const int* __restrict__ aux,
                                                  int* __restrict__ csr) {
    int e = blockIdx.x * 256 + threadIdx.x;
    if (e < N_EDGES) csr[rowoff[dst[e]] + aux[e]] = src[e];
}

// ---------------- xs = dinv[n] * x (bf16, RNE) ----------------
__global__ __launch_bounds__(256) void xconvert(const float* __restrict__ x,
                                                const float* __restrict__ dinv,
                                                u16* __restrict__ xs) {
    int i = blockIdx.x * 256 + threadIdx.x;      // exactly 3.2M threads (float4 units)
    int n = i >> 5;                              // 32 float4 per row
    float dd = dinv[n];
    float4 v = ((const float4*)x)[i];
    ushort4 o;
    o.x = f2bf(v.x * dd); o.y = f2bf(v.y * dd);
    o.z = f2bf(v.z * dd); o.w = f2bf(v.w * dd);
    ((ushort4*)xs)[i] = o;
}

// W1 [k][n] f32 -> W1t [n][k] bf16
__global__ __launch_bounds__(256) void wconvert(const float* __restrict__ W1,
                                                u16* __restrict__ W1t) {
    int i = blockIdx.x * 256 + threadIdx.x;      // 16384
    int k = i >> 7, n = i & 127;
    W1t[n * H_DIM + k] = f2bf(W1[k * H_DIM + n]);
}

// ------- gather layer 1: aggb[n] = bf16( dinv[n] * sum_{s in N(n)} xs[s] ) --
// 16 lanes/node (8 ch each, int4), 16 nodes/block, 4-edge unroll.
__global__ __launch_bounds__(256) void gather_x(const int* __restrict__ rowoff,
                                                const int* __restrict__ csr,
                                                const float* __restrict__ dinv,
                                                const u16* __restrict__ xs,
                                                u16* __restrict__ aggb) {
    int node = blockIdx.x * 16 + (threadIdx.x >> 4);     // grid exact: N%16==0
    int q = threadIdx.x & 15;
    int beg = rowoff[node], end = rowoff[node + 1];
    float acc[8] = {};
    int e = beg;
    for (; e + 3 < end; e += 4) {
        int s0 = csr[e], s1 = csr[e + 1], s2 = csr[e + 2], s3 = csr[e + 3];
        int4 v0 = *(const int4*)(xs + (size_t)s0 * F_IN + q * 8);
        int4 v1 = *(const int4*)(xs + (size_t)s1 * F_IN + q * 8);
        int4 v2 = *(const int4*)(xs + (size_t)s2 * F_IN + q * 8);
        int4 v3 = *(const int4*)(xs + (size_t)s3 * F_IN + q * 8);
        add2(&acc[0], &acc[1], (u32)v0.x); add2(&acc[2], &acc[3], (u32)v0.y);
        add2(&acc[4], &acc[5], (u32)v0.z); add2(&acc[6], &acc[7], (u32)v0.w);
        add2(&acc[0], &acc[1], (u32)v1.x); add2(&acc[2], &acc[3], (u32)v1.y);
        add2(&acc[4], &acc[5], (u32)v1.z); add2(&acc[6], &acc[7], (u32)v1.w);
        add2(&acc[0], &acc[1], (u32)v2.x); add2(&acc[2], &acc[3], (u32)v2.y);
        add2(&acc[4], &acc[5], (u32)v2.z); add2(&acc[6], &acc[7], (u32)v2.w);
        add2(&acc[0], &acc[1], (u32)v3.x); add2(&acc[2], &acc[3], (u32)v3.y);
        add2(&acc[4], &acc[5], (u32)v3.z); add2(&acc[6], &acc[7], (u32)v3.w);
    }
    for (; e < end; ++e) {
        int s = csr[e];
        int4 v = *(const int4*)(xs + (size_t)s * F_IN + q * 8);
        add2(&acc[0], &acc[1], (u32)v.x); add2(&acc[2], &acc[3], (u32)v.y);
        add2(&acc[4], &acc[5], (u32)v.z); add2(&acc[6], &acc[7], (u32)v.w);
    }
    float dd = dinv[node];
    int4 o;
    o.x = (int)((u32)f2bf(acc[0] * dd) | ((u32)f2bf(acc[1] * dd) << 16));
    o.y = (int)((u32)f2bf(acc[2] * dd) | ((u32)f2bf(acc[3] * dd) << 16));
    o.z = (int)((u32)f2bf(acc[4] * dd) | ((u32)f2bf(acc[5] * dd) << 16));
    o.w = (int)((u32)f2bf(acc[6] * dd) | ((u32)f2bf(acc[7] * dd) << 16));
    *(int4*)(aggb + (size_t)node * H_DIM + q * 8) = o;
}

// ------------- GEMM1 via MFMA: hb = relu(aggb@W1 + b1) (bf16) --------------
// BN partial stats -> pstats[c][blk], plain stores.
__global__ __launch_bounds__(256) void gemm1_mfma(const u16* __restrict__ aggb,
                                                  const u16* __restrict__ W1t,
                                                  const float* __restrict__ b1,
                                                  u16* __restrict__ hb,
                                                  float* __restrict__ pstats) {
    __shared__ u16 As[G1_ROWS * G1_LD];   // 34.8 KB
    int tid = threadIdx.x;
    int base = blockIdx.x * G1_ROWS;

    {   // stage 128 node rows (256 B each), clamped at tail
        int row = tid >> 1, half = tid & 1;
        int gr = base + row; if (gr >= N_NODES) gr = N_NODES - 1;
        const int4* gsrc = (const int4*)(aggb + (size_t)gr * H_DIM + half * 64);
        int4* ldst = (int4*)(As + row * G1_LD + half * 64);
        #pragma unroll
        for (int i = 0; i < 8; ++i) ldst[i] = gsrc[i];
    }
    __syncthreads();

    int lane = tid & 63, w = tid >> 6;
    int r = lane & 15, g = lane >> 4;

    bf16x8 wf[2][4];   // [ch-tile][kstep], resident
    #pragma unroll
    for (int t = 0; t < 2; ++t)
        #pragma unroll
        for (int ks = 0; ks < 4; ++ks)
            wf[t][ks] = *(const bf16x8*)(W1t + (w * 32 + t * 16 + r) * H_DIM + ks * 32 + g * 8);

    float bch[2][4];
    #pragma unroll
    for (int t = 0; t < 2; ++t)
        #pragma unroll
        for (int i = 0; i < 4; ++i)
            bch[t][i] = b1[w * 32 + t * 16 + 4 * g + i];

    float cs[8] = {}, cq[8] = {};

    for (int rt = 0; rt < 8; ++rt) {
        f32x4 acc0 = {0.f, 0.f, 0.f, 0.f}, acc1 = {0.f, 0.f, 0.f, 0.f};
        #pragma unroll
        for (int ks = 0; ks < 4; ++ks) {
            bf16x8 nf = *(const bf16x8*)(As + (rt * 16 + r) * G1_LD + ks * 32 + g * 8);
            acc0 = __builtin_amdgcn_mfma_f32_16x16x32_bf16(wf[0][ks], nf, acc0, 0, 0, 0);
            acc1 = __builtin_amdgcn_mfma_f32_16x16x32_bf16(wf[1][ks], nf, acc1, 0, 0, 0);
        }
        int node = base + rt * 16 + r;
        if (node < N_NODES) {
            float o0[4], o1[4];
            #pragma unroll
            for (int i = 0; i < 4; ++i) {
                o0[i] = fmaxf(acc0[i] + bch[0][i], 0.f);
                o1[i] = fmaxf(acc1[i] + bch[1][i], 0.f);
                cs[i]     += o0[i]; cq[i]     += o0[i] * o0[i];
                cs[4 + i] += o1[i]; cq[4 + i] += o1[i] * o1[i];
            }
            uint2 p0, p1;
            p0.x = (u32)f2bf(o0[0]) | ((u32)f2bf(o0[1]) << 16);
            p0.y = (u32)f2bf(o0[2]) | ((u32)f2bf(o0[3]) << 16);
            p1.x = (u32)f2bf(o1[0]) | ((u32)f2bf(o1[1]) << 16);
            p1.y = (u32)f2bf(o1[2]) | ((u32)f2bf(o1[3]) << 16);
            u16* hp = hb + (size_t)node * H_DIM + w * 32 + 4 * g;
            *(uint2*)hp = p0;
            *(uint2*)(hp + 16) = p1;
        }
    }

    #pragma unroll
    for (int j = 0; j < 8; ++j) {
        #pragma unroll
        for (int m = 1; m < 16; m <<= 1) {
            cs[j] += __shfl_xor(cs[j], m, 16);
            cq[j] += __shfl_xor(cq[j], m, 16);
        }
    }
    if (r == 0) {
        #pragma unroll
        for (int j = 0; j < 8; ++j) {
            int c = w * 32 + (j >> 2) * 16 + 4 * g + (j & 3);
            pstats[c * PS_LD + blockIdx.x] = cs[j];
            pstats[(128 + c) * PS_LD + blockIdx.x] = cq[j];
        }
    }
}

// ---- reduce per-block partials -> scale/shift (one block per channel) ----
__global__ __launch_bounds__(256) void stats_final(const float* __restrict__ pstats,
                                                   const float* __restrict__ gamma,
                                                   const float* __restrict__ beta,
                                                   float* __restrict__ scale,
                                                   float* __restrict__ shift) {
    __shared__ float ls[256], lq[256];
    int c = blockIdx.x, t = threadIdx.x;
    float s = 0.f, q = 0.f;
    for (int b = t; b < G1_NB; b += 256) {
        s += pstats[c * PS_LD + b];
        q += pstats[(128 + c) * PS_LD + b];
    }
    ls[t] = s; lq[t] = q;
    __syncthreads();
    for (int off = 128; off; off >>= 1) {
        if (t < off) { ls[t] += ls[t + off]; lq[t] += lq[t + off]; }
        __syncthreads();
    }
    if (t == 0) {
        const float invn = 1.0f / (float)N_NODES;
        float mean = ls[0] * invn;
        float var = lq[0] * invn - mean * mean;
        float sc = gamma[c] * rsqrtf(var + BN_EPS);
        scale[c] = sc;
        shift[c] = beta[c] - mean * sc;
    }
}

// ---- fold BN into layer-2 weights: W2t[c][k] = bf16(scale[k]*W2[k][c]),
// padded to 48 channels; K[c] = sum_k shift[k]*W2[k][c] (f32, 48 entries) ----
__global__ __launch_bounds__(256) void w2fold(const float* __restrict__ W2,
                                              const float* __restrict__ scale,
                                              const float* __restrict__ shift,
                                              u16* __restrict__ W2t,
                                              float* __restrict__ K) {
    int t = threadIdx.x;
    for (int i = t; i < 48 * 128; i += 256) {
        int c = i >> 7, k = i & 127;
        W2t[i] = (c < C_OUT) ? f2bf(scale[k] * W2[k * C_OUT + c]) : (u16)0;
    }
    if (t < 48) {
        float a = 0.f;
        if (t < C_OUT)
            for (int k = 0; k < H_DIM; ++k) a += shift[k] * W2[k * C_OUT + t];
        K[t] = a;
    }
}

// ---- GEMM2 via MFMA: h2s[n] = bf16( dinv[n] * (hb[n]@W2t + K) )  (48 ch) ---
__global__ __launch_bounds__(256) void gemm2_mfma(const u16* __restrict__ hb,
                                                  const u16* __restrict__ W2t,
                                                  const float* __restrict__ K,
                                                  const float* __restrict__ dinv,
                                                  u16* __restrict__ h2s) {
    __shared__ u16 As[G1_ROWS * G1_LD];
    int tid = threadIdx.x;
    int base = blockIdx.x * G1_ROWS;

    {
        int row = tid >> 1, half = tid & 1;
        int gr = base + row; if (gr >= N_NODES) gr = N_NODES - 1;
        const int4* gsrc = (const int4*)(hb + (size_t)gr * H_DIM + half * 64);
        int4* ldst = (int4*)(As + row * G1_LD + half * 64);
        #pragma unroll
        for (int i = 0; i < 8; ++i) ldst[i] = gsrc[i];
    }
    __syncthreads();

    int lane = tid & 63, w = tid >> 6;
    int r = lane & 15, g = lane >> 4;

    bf16x8 wf[3][4];
    #pragma unroll
    for (int t = 0; t < 3; ++t)
        #pragma unroll
        for (int ks = 0; ks < 4; ++ks)
            wf[t][ks] = *(const bf16x8*)(W2t + (t * 16 + r) * H_DIM + ks * 32 + g * 8);

    float kv[3][4];
    #pragma unroll
    for (int t = 0; t < 3; ++t)
        #pragma unroll
        for (int i = 0; i < 4; ++i)
            kv[t][i] = K[t * 16 + 4 * g + i];

    f32x4 acc[2][3];
    #pragma unroll
    for (int i2 = 0; i2 < 2; ++i2)
        #pragma unroll
        for (int t = 0; t < 3; ++t)
            acc[i2][t] = (f32x4){0.f, 0.f, 0.f, 0.f};

    #pragma unroll
    for (int i2 = 0; i2 < 2; ++i2) {
        int rt = 2 * w + i2;
        #pragma unroll
        for (int ks = 0; ks < 4; ++ks) {
            bf16x8 nf = *(const bf16x8*)(As + (rt * 16 + r) * G1_LD + ks * 32 + g * 8);
            acc[i2][0] = __builtin_amdgcn_mfma_f32_16x16x32_bf16(wf[0][ks], nf, acc[i2][0], 0, 0, 0);
            acc[i2][1] = __builtin_amdgcn_mfma_f32_16x16x32_bf16(wf[1][ks], nf, acc[i2][1], 0, 0, 0);
            acc[i2][2] = __builtin_amdgcn_mfma_f32_16x16x32_bf16(wf[2][ks], nf, acc[i2][2], 0, 0, 0);
        }
    }

    #pragma unroll
    for (int i2 = 0; i2 < 2; ++i2) {
        int node = base + (2 * w + i2) * 16 + r;
        if (node < N_NODES) {
            float dd = dinv[node];
            u16* hp = h2s + (size_t)node * C_OUT + 4 * g;
            #pragma unroll
            for (int t = 0; t < 2; ++t) {
                uint2 p;
                p.x = (u32)f2bf((acc[i2][t][0] + kv[t][0]) * dd) |
                      ((u32)f2bf((acc[i2][t][1] + kv[t][1]) * dd) << 16);
                p.y = (u32)f2bf((acc[i2][t][2] + kv[t][2]) * dd) |
                      ((u32)f2bf((acc[i2][t][3] + kv[t][3]) * dd) << 16);
                *(uint2*)(hp + t * 16) = p;
            }
            if (g < 2) {
                uint2 p;
                p.x = (u32)f2bf((acc[i2][2][0] + kv[2][0]) * dd) |
                      ((u32)f2bf((acc[i2][2][1] + kv[2][1]) * dd) << 16);
                p.y = (u32)f2bf((acc[i2][2][2] + kv[2][2]) * dd) |
                      ((u32)f2bf((acc[i2][2][3] + kv[2][3]) * dd) << 16);
                *(uint2*)(hp + 32) = p;
            }
        }
    }
}

// --- gather layer 2: out[n] = logsoftmax(dinv[n]*sum h2s[s] + b2), 16 ln/node
__global__ __launch_bounds__(256) void gather2_fused(const int* __restrict__ rowoff,
                                                     const int* __restrict__ csr,
                                                     const float* __restrict__ dinv,
                                                     const u16* __restrict__ h2s,
                                                     const float* __restrict__ b2,
                                                     float* __restrict__ out) {
    int node = blockIdx.x * 16 + (threadIdx.x >> 4);     // grid exact: N%16==0
    int q = threadIdx.x & 15;
    int beg = rowoff[node], end = rowoff[node + 1];
    float a0 = 0.f, a1 = 0.f, a2 = 0.f, a3 = 0.f;
    int e = beg;
    for (; e + 3 < end; e += 4) {
        int s0 = csr[e], s1 = csr[e + 1], s2 = csr[e + 2], s3 = csr[e + 3];
        if (q < 10) {
            uint2 v0 = *(const uint2*)(h2s + (size_t)s0 * C_OUT + q * 4);
            uint2 v1 = *(const uint2*)(h2s + (size_t)s1 * C_OUT + q * 4);
            uint2 v2 = *(const uint2*)(h2s + (size_t)s2 * C_OUT + q * 4);
            uint2 v3 = *(const uint2*)(h2s + (size_t)s3 * C_OUT + q * 4);
            add2(&a0, &a1, v0.x); add2(&a2, &a3, v0.y);
            add2(&a0, &a1, v1.x); add2(&a2, &a3, v1.y);
            add2(&a0, &a1, v2.x); add2(&a2, &a3, v2.y);
            add2(&a0, &a1, v3.x); add2(&a2, &a3, v3.y);
        }
    }
    for (; e < end; ++e) {
        int s = csr[e];
        if (q < 10) {
            uint2 v = *(const uint2*)(h2s + (size_t)s * C_OUT + q * 4);
            add2(&a0, &a1, v.x); add2(&a2, &a3, v.y);
        }
    }
    float dd = dinv[node];
    float4 r;
    float m = -INFINITY;
    if (q < 10) {
        float4 bv = *(const float4*)(b2 + q * 4);
        r.x = fmaf(a0, dd, bv.x); r.y = fmaf(a1, dd, bv.y);
        r.z = fmaf(a2, dd, bv.z); r.w = fmaf(a3, dd, bv.w);
        m = fmaxf(fmaxf(r.x, r.y), fmaxf(r.z, r.w));
    }
    #pragma unroll
    for (int off = 1; off < 16; off <<= 1) m = fmaxf(m, __shfl_xor(m, off, 16));
    float ex = 0.f;
    if (q < 10)
        ex = expf(r.x - m) + expf(r.y - m) + expf(r.z - m) + expf(r.w - m);
    #pragma unroll
    for (int off = 1; off < 16; off <<= 1) ex += __shfl_xor(ex, off, 16);
    float lse = logf(ex) + m;
    if (q < 10) {
        float4 o = {r.x - lse, r.y - lse, r.z - lse, r.w - lse};
        *(float4*)(out + (size_t)node * C_OUT + q * 4) = o;
    }
}

// ---------------- launch ----------------
extern "C" void kernel_launch(void* const* d_in, const int* in_sizes, int n_in,
                              void* d_out, int out_size, void* d_ws, size_t ws_size,
                              hipStream_t stream) {
    const float* x     = (const float*)d_in[0];
    const int*   eidx  = (const int*)d_in[1];
    const float* W1    = (const float*)d_in[2];
    const float* b1    = (const float*)d_in[3];
    const float* gamma = (const float*)d_in[4];
    const float* beta  = (const float*)d_in[5];
    const float* W2    = (const float*)d_in[6];
    const float* b2    = (const float*)d_in[7];
    float* out = (float*)d_out;

    const int* src = eidx;
    const int* dst = eidx + N_EDGES;

    // workspace layout (4B units)
    float* ws = (float*)d_ws;
    int*   cnt    = (int*)ws;                  // N
    float* dinv   = ws + 100000;               // N
    int*   rowoff = (int*)(ws + 200000);       // N+1
    int*   bsum   = (int*)(ws + 300032);       // SCAN_NB
    int*   aux    = (int*)(ws + 301056);       // E
    int*   csr    = (int*)(ws + 1901056);      // NSEG
    u16*   xs     = (u16*)(ws + 3601056);      // N*128 bf16; hb aliases (xs dead after gather_x)
    u16*   hb     = (u16*)(ws + 3601056);
    u16*   aggb   = (u16*)(ws + 10001056);     // N*128 bf16
    u16*   W1t    = (u16*)(ws + 16401056);     // 128*128 bf16
    u16*   h2s    = (u16*)(ws + 16409248);     // N*40 bf16 (dinv-scaled h2)
    float* pstats = ws + 18409248;             // 256*800 f32
    float* scale  = ws + 18614048;             // 128
    float* shift  = ws + 18614176;             // 128
    float* K      = ws + 18614304;             // 48 (+pad)
    u16*   W2t    = (u16*)(ws + 18614368);     // 48*128 bf16

    size_t needed = (size_t)(18614368 + 1536) * 4;
    if (ws_size < needed) return;

    // CSR build (atomic-free fill)
    cnt_init<<<(N_NODES + 255) / 256, 256, 0, stream>>>(cnt);
    cnt_count<<<(N_EDGES + 255) / 256, 256, 0, stream>>>(dst, cnt, aux);
    scan_block<<<SCAN_NB, SCAN_T, 0, stream>>>(cnt, rowoff, bsum);
    scan_bsum<<<1, 256, 0, stream>>>(bsum);
    scan_add<<<SCAN_NB, SCAN_T, 0, stream>>>(rowoff, bsum);
    dinv_self<<<(N_NODES + 255) / 256, 256, 0, stream>>>(cnt, rowoff, dinv, csr);
    fill_edges<<<(N_EDGES + 255) / 256, 256, 0, stream>>>(src, dst, rowoff, aux, csr);

    // layer 1
    xconvert<<<N_NODES * F_IN / 4 / 256, 256, 0, stream>>>(x, dinv, xs);
    wconvert<<<F_IN * H_DIM / 256, 256, 0, stream>>>(W1, W1t);
    gather_x<<<N_NODES / 16, 256, 0, stream>>>(rowoff, csr, dinv, xs, aggb);
    gemm1_mfma<<<G1_NB, 256, 0, stream>>>(aggb, W1t, b1, hb, pstats);
    stats_final<<<128, 256, 0, stream>>>(pstats, gamma, beta, scale, shift);
    w2fold<<<1, 256, 0, stream>>>(W2, scale, shift, W2t, K);

    // layer 2
    gemm2_mfma<<<G1_NB, 256, 0, stream>>>(hb, W2t, K, dinv, h2s);
    gather2_fused<<<N_NODES / 16, 256, 0, stream>>>(rowoff, csr, dinv, h2s, b2, out);
}